// Round 26
// baseline (759.733 us; speedup 1.0000x reference)
//
#include <hip/hip_runtime.h>

#define NN 100000      // nodes
#define NE 300000      // edges
#define GPLANE 528     // shorts per LDS fragment plane (512 + 16 pad)

typedef float f32x4 __attribute__((ext_vector_type(4)));
typedef __bf16 bf16x8 __attribute__((ext_vector_type(8)));
typedef unsigned short ushort8v __attribute__((ext_vector_type(8)));

// ---------- helpers ----------
__device__ __forceinline__ int enc_f(float f) {
    int i = __float_as_int(f);
    return i >= 0 ? i : (i ^ 0x7fffffff);
}
__device__ __forceinline__ float dec_f(int i) {
    return __int_as_float(i >= 0 ? i : (i ^ 0x7fffffff));
}
__device__ __forceinline__ unsigned short f2bf(float f) {
    unsigned u = __float_as_uint(f);
    u += 0x7fffu + ((u >> 16) & 1u);
    return (unsigned short)(u >> 16);
}
__device__ __forceinline__ float bf2f(unsigned short u) {
    return __uint_as_float((unsigned)u << 16);
}

__global__ void k_dbg(float* out, float v) { out[0] = v; out[1] = v; }

__global__ void k_fill_i32(int* p, int v, int n) {
    int i = blockIdx.x * 256 + threadIdx.x;
    if (i < n) p[i] = v;
}

// pack W[o][off+k] (row stride `stride`) -> fragment-major bf16
__global__ void k_pack_w_sub(const float* __restrict__ src, unsigned short* __restrict__ dst,
                             int OUT, int K, int stride, int off) {
    int i = blockIdx.x * 256 + threadIdx.x;
    if (i >= OUT * K) return;
    int o = i / K, k = i % K;
    int ob = o >> 6, n = (o >> 4) & 3, fr = o & 15;
    int step = k >> 5, kq = (k >> 3) & 3, j = k & 7;
    size_t dsti = ((((size_t)step * (OUT >> 6) + ob) * 4 + n) * 64 + (kq * 16 + fr)) * 8 + j;
    dst[dsti] = f2bf(src[(size_t)o * stride + off + k]);
}

// Mtd[o][i] = sum_c W1d[o][c] * tw2[c][i] ; b1eff[o] = b1[o] + sum_c W1d[o][c]*tb2[c]
__global__ void k_fold_te(const float* __restrict__ msg_w1, const float* __restrict__ tw2,
                          const float* __restrict__ tb2, const float* __restrict__ b1,
                          float* __restrict__ Mtd, float* __restrict__ b1eff) {
    int i = blockIdx.x * 256 + threadIdx.x;
    if (i < 256 * 32) {
        int o = i >> 5, col = i & 31;
        float s = 0.f;
        const float* w1d = msg_w1 + (size_t)o * 576 + 544;
#pragma unroll
        for (int c = 0; c < 32; ++c) s += w1d[c] * tw2[c * 32 + col];
        Mtd[i] = s;
        if (col == 0) {
            float sb = b1[o];
#pragma unroll
            for (int c = 0; c < 32; ++c) sb += w1d[c] * tb2[c];
            b1eff[o] = sb;
        }
    }
}

__global__ void k_timemax(const float* __restrict__ ts, int n, int* out) {
    float m = -INFINITY;
    int stride = gridDim.x * blockDim.x;
    for (int i = blockIdx.x * blockDim.x + threadIdx.x; i < n; i += stride)
        m = fmaxf(m, ts[i]);
    atomicMax(out, enc_f(m));
}

__global__ void k_counts(const int* __restrict__ ei, float* __restrict__ counts) {
    int stride = gridDim.x * blockDim.x;
    for (int i = blockIdx.x * blockDim.x + threadIdx.x; i < NE; i += stride)
        atomicAdd(&counts[ei[NE + i]], 1.f);
}

// ---------- CSR build ----------
__global__ void k_scan1(const float* __restrict__ counts, int* __restrict__ rowptr,
                        int* __restrict__ bsum) {
    __shared__ int sh[256];
    int t = threadIdx.x;
    int i = blockIdx.x * 256 + t;
    int v = (i < NN) ? ((int)counts[i] + 1) : 0;
    sh[t] = v;
    __syncthreads();
    for (int off = 1; off < 256; off <<= 1) {
        int x = (t >= off) ? sh[t - off] : 0;
        __syncthreads();
        sh[t] += x;
        __syncthreads();
    }
    if (i < NN) rowptr[i + 1] = sh[t];
    if (t == 255) bsum[blockIdx.x] = sh[255];
}

__global__ void k_scan2(int* __restrict__ bsum, int nb) {
    __shared__ int sh[512];
    int t = threadIdx.x;
    sh[t] = (t < nb) ? bsum[t] : 0;
    __syncthreads();
    for (int off = 1; off < 512; off <<= 1) {
        int x = (t >= off) ? sh[t - off] : 0;
        __syncthreads();
        sh[t] += x;
        __syncthreads();
    }
    if (t < nb) bsum[t] = sh[t];
}

// finalize rowptr and seed both fill cursors (node CSR + edge-only list)
__global__ void k_scan3(int* __restrict__ rowptr, const int* __restrict__ bsum,
                        int* __restrict__ fillp, int* __restrict__ fillE) {
    int i = blockIdx.x * 256 + threadIdx.x;
    if (i == 0) {
        rowptr[0] = 0;
        fillp[0] = 0;
        fillE[0] = 0;
    }
    if (i < NN) {
        int b = i >> 8;
        int off = b > 0 ? bsum[b - 1] : 0;
        int v = rowptr[i + 1] + off;
        rowptr[i + 1] = v;
        if (i + 1 < NN) {
            fillp[i + 1] = v;
            fillE[i + 1] = v - (i + 1);
        }
    }
}

__global__ void k_csr_fill(const int* __restrict__ ei, int* __restrict__ fill,
                           int* __restrict__ colidx) {
    int i = blockIdx.x * 256 + threadIdx.x;
    if (i < NE) {
        int d = ei[NE + i];
        int pos = atomicAdd(&fill[d], 1);
        colidx[pos] = ei[i];
    } else if (i < NE + NN) {
        int n = i - NE;
        int pos = atomicAdd(&fill[n], 1);
        colidx[pos] = n;
    }
}

__global__ void k_ecsr_fill(const int* __restrict__ ei, int* __restrict__ fillE,
                            int* __restrict__ esrc, int* __restrict__ edst) {
    int i = blockIdx.x * 256 + threadIdx.x;
    if (i < NE) {
        int d = ei[NE + i];
        int pos = atomicAdd(&fillE[d], 1);
        esrc[pos] = ei[i];
        edst[pos] = d;
    }
}

// ---------- per-node precompute: P13/P2 + bf16 copy of mem (membf) ----------
__global__ __launch_bounds__(512, 4) void k_pre1(
    const float* __restrict__ mem, const float* __restrict__ x,
    const unsigned short* __restrict__ w1ap, const unsigned short* __restrict__ w1bp,
    const unsigned short* __restrict__ w1cp,
    unsigned short* __restrict__ P13, unsigned short* __restrict__ P2,
    unsigned short* __restrict__ membf) {
    __shared__ unsigned short Af[2 * 8 * GPLANE];
    __shared__ unsigned short Axf[2 * 512];
    const int t = threadIdx.x;
    const int lane = t & 63, w = t >> 6;
    const int row0 = blockIdx.x * 32;
    const int frow = lane & 15, hi = lane >> 4;
    const int half = w >> 2, cq = w & 3;

    {
        int sr = t >> 4, sq = t & 15;
        int row = row0 + sr;
        const float* pm = mem + (size_t)row * 256 + sq * 16;
        int smq = sr >> 4, sfr = sr & 15;
#pragma unroll
        for (int j2 = 0; j2 < 2; ++j2) {
            int k8 = sq * 16 + j2 * 8;
            int st = k8 >> 5, kq = (k8 >> 3) & 3;
            float4 m0 = *(const float4*)(pm + j2 * 8);
            float4 m1 = *(const float4*)(pm + j2 * 8 + 4);
            ushort8v um;
            um[0] = f2bf(m0.x); um[1] = f2bf(m0.y); um[2] = f2bf(m0.z); um[3] = f2bf(m0.w);
            um[4] = f2bf(m1.x); um[5] = f2bf(m1.y); um[6] = f2bf(m1.z); um[7] = f2bf(m1.w);
            *(ushort8v*)&Af[((smq * 8) + st) * GPLANE + (kq * 16 + sfr) * 8] = um;
            *(ushort8v*)(membf + (size_t)row * 256 + k8) = um;
        }
    }
    if (t < 128) {
        int sr = t >> 2, sq = t & 3;
        int row = row0 + sr;
        const float* px = x + (size_t)row * 32 + sq * 8;
        float4 v0 = *(const float4*)px, v1 = *(const float4*)(px + 4);
        ushort8v u;
        u[0] = f2bf(v0.x); u[1] = f2bf(v0.y); u[2] = f2bf(v0.z); u[3] = f2bf(v0.w);
        u[4] = f2bf(v1.x); u[5] = f2bf(v1.y); u[6] = f2bf(v1.z); u[7] = f2bf(v1.w);
        *(ushort8v*)&Axf[(sr >> 4) * 512 + (sq * 16 + (sr & 15)) * 8] = u;
    }
    __syncthreads();

    f32x4 acc[2][4];
#pragma unroll
    for (int mf = 0; mf < 2; ++mf)
#pragma unroll
        for (int c = 0; c < 4; ++c) acc[mf][c] = (f32x4){0, 0, 0, 0};

    const unsigned short* wp = half ? w1bp : w1ap;
    for (int step = 0; step < 8; ++step) {
        bf16x8 aA[2];
#pragma unroll
        for (int mf = 0; mf < 2; ++mf)
            aA[mf] = *(const bf16x8*)&Af[((mf * 8) + step) * GPLANE + lane * 8];
#pragma unroll
        for (int ctl = 0; ctl < 4; ++ctl) {
            bf16x8 b = *(const bf16x8*)(wp + (((size_t)step * 4 + cq) * 4 + ctl) * 512 + lane * 8);
#pragma unroll
            for (int mf = 0; mf < 2; ++mf)
                acc[mf][ctl] = __builtin_amdgcn_mfma_f32_16x16x32_bf16(aA[mf], b, acc[mf][ctl], 0, 0, 0);
        }
    }
    if (half == 0) {
        bf16x8 aX[2];
#pragma unroll
        for (int mf = 0; mf < 2; ++mf)
            aX[mf] = *(const bf16x8*)&Axf[mf * 512 + lane * 8];
#pragma unroll
        for (int ctl = 0; ctl < 4; ++ctl) {
            bf16x8 b = *(const bf16x8*)(w1cp + (((size_t)0 * 4 + cq) * 4 + ctl) * 512 + lane * 8);
#pragma unroll
            for (int mf = 0; mf < 2; ++mf)
                acc[mf][ctl] = __builtin_amdgcn_mfma_f32_16x16x32_bf16(aX[mf], b, acc[mf][ctl], 0, 0, 0);
        }
    }
    unsigned short* P = half ? P2 : P13;
#pragma unroll
    for (int mf = 0; mf < 2; ++mf)
#pragma unroll
        for (int ctl = 0; ctl < 4; ++ctl) {
            int col = cq * 64 + ctl * 16 + frow;
#pragma unroll
            for (int r = 0; r < 4; ++r) {
                int row = row0 + mf * 16 + hi * 4 + r;
                P[(size_t)row * 256 + col] = f2bf(acc[mf][ctl][r]);
            }
        }
}

// ---------- edge message kernel, 512 thr (8 waves x 64x32 out) ----------
__global__ __launch_bounds__(512, 4) void k_msg_mfma(
    const int* __restrict__ ct, const float* __restrict__ lut,
    const int* __restrict__ esrc, const int* __restrict__ edst,
    const unsigned short* __restrict__ P13, const unsigned short* __restrict__ P2,
    const unsigned short* __restrict__ wtdp, const float* __restrict__ b1eff,
    const unsigned short* __restrict__ w2p, const float* __restrict__ b2,
    const float* __restrict__ tw1, const float* __restrict__ tb1,
    float* __restrict__ agg) {
    __shared__ unsigned short As[64][40];
    __shared__ unsigned short Hs[64][264];
    __shared__ int Da[64];

    const int t = threadIdx.x;
    const int lane = t & 63, wave = t >> 6;
    const int row0 = blockIdx.x * 64;
    const int frow = lane & 15;
    const int fk = (lane >> 4) * 8;
    const int hi = lane >> 4;
    const int wb = wave >> 1;
    const int wn = (wave & 1) * 2;

    if (t < 64) {
        int e = row0 + t;
        Da[t] = (e < NE) ? edst[e] : -1;
    }

    const int srow = t >> 3;
    const int sj = t & 7;
    const int eIdx = row0 + srow;
    const bool ev = eIdx < NE;
    const int s_e = ev ? esrc[eIdx] : 0;
    const int d_e = ev ? edst[eIdx] : 0;

    {
        float ctv = dec_f(*ct);
        float dt = ev ? (ctv - fmaxf(lut[s_e], lut[d_e])) : 0.f;
        ushort4 u;
        int c0 = sj * 4;
        u.x = f2bf(fmaxf(dt * tw1[c0 + 0] + tb1[c0 + 0], 0.f));
        u.y = f2bf(fmaxf(dt * tw1[c0 + 1] + tb1[c0 + 1], 0.f));
        u.z = f2bf(fmaxf(dt * tw1[c0 + 2] + tb1[c0 + 2], 0.f));
        u.w = f2bf(fmaxf(dt * tw1[c0 + 3] + tb1[c0 + 3], 0.f));
        *(ushort4*)&As[srow][c0] = u;
    }
#pragma unroll
    for (int q = 0; q < 4; ++q) {
        int c = sj * 8 + q * 64;
        ushort4 a0 = *(const ushort4*)(P13 + (size_t)s_e * 256 + c);
        ushort4 a1 = *(const ushort4*)(P13 + (size_t)s_e * 256 + c + 4);
        ushort4 b0 = *(const ushort4*)(P2 + (size_t)d_e * 256 + c);
        ushort4 b1v = *(const ushort4*)(P2 + (size_t)d_e * 256 + c + 4);
        ushort8v u;
        u[0] = f2bf(bf2f(a0.x) + bf2f(b0.x)); u[1] = f2bf(bf2f(a0.y) + bf2f(b0.y));
        u[2] = f2bf(bf2f(a0.z) + bf2f(b0.z)); u[3] = f2bf(bf2f(a0.w) + bf2f(b0.w));
        u[4] = f2bf(bf2f(a1.x) + bf2f(b1v.x)); u[5] = f2bf(bf2f(a1.y) + bf2f(b1v.y));
        u[6] = f2bf(bf2f(a1.z) + bf2f(b1v.z)); u[7] = f2bf(bf2f(a1.w) + bf2f(b1v.w));
        *(ushort8v*)&Hs[srow][c] = u;
    }
    __syncthreads();

    f32x4 acc[4][2];
#pragma unroll
    for (int m = 0; m < 4; m++)
#pragma unroll
        for (int n = 0; n < 2; n++) acc[m][n] = (f32x4){0.f, 0.f, 0.f, 0.f};

    {
        bf16x8 a[4];
#pragma unroll
        for (int m = 0; m < 4; m++)
            a[m] = *(const bf16x8*)&As[m * 16 + frow][fk];
#pragma unroll
        for (int n = 0; n < 2; n++) {
            bf16x8 b = *(const bf16x8*)(wtdp + (((size_t)0 * 4 + wb) * 4 + (wn + n)) * 512 + lane * 8);
#pragma unroll
            for (int m = 0; m < 4; m++)
                acc[m][n] = __builtin_amdgcn_mfma_f32_16x16x32_bf16(a[m], b, acc[m][n], 0, 0, 0);
        }
    }
#pragma unroll
    for (int n = 0; n < 2; n++) {
        int c = wave * 32 + n * 16 + frow;
        float bb = b1eff[c];
#pragma unroll
        for (int m = 0; m < 4; m++) {
#pragma unroll
            for (int r = 0; r < 4; r++) {
                int rr = m * 16 + hi * 4 + r;
                float v = acc[m][n][r] + bf2f(Hs[rr][c]) + bb;
                Hs[rr][c] = f2bf(fmaxf(v, 0.f));
            }
            acc[m][n] = (f32x4){0.f, 0.f, 0.f, 0.f};
        }
    }
    __syncthreads();

    bf16x8 bnext[2];
#pragma unroll
    for (int n = 0; n < 2; n++)
        bnext[n] = *(const bf16x8*)(w2p + (((size_t)0 * 4 + wb) * 4 + (wn + n)) * 512 + lane * 8);
    for (int step = 0; step < 8; ++step) {
        const int k0 = step * 32;
        bf16x8 bcur[2];
#pragma unroll
        for (int n = 0; n < 2; n++) bcur[n] = bnext[n];
        if (step < 7) {
#pragma unroll
            for (int n = 0; n < 2; n++)
                bnext[n] = *(const bf16x8*)(w2p + (((size_t)(step + 1) * 4 + wb) * 4 + (wn + n)) * 512 + lane * 8);
        }
        bf16x8 a[4];
#pragma unroll
        for (int m = 0; m < 4; m++)
            a[m] = *(const bf16x8*)&Hs[m * 16 + frow][k0 + fk];
#pragma unroll
        for (int m = 0; m < 4; m++)
#pragma unroll
            for (int n = 0; n < 2; n++)
                acc[m][n] = __builtin_amdgcn_mfma_f32_16x16x32_bf16(a[m], bcur[n], acc[m][n], 0, 0, 0);
    }

    __syncthreads();
    {
        float bb2[2];
#pragma unroll
        for (int n = 0; n < 2; n++) bb2[n] = b2[wave * 32 + n * 16 + frow];
#pragma unroll
        for (int m = 0; m < 4; m++) {
            int rbase = m * 16 + hi * 4;
#pragma unroll
            for (int r = 0; r < 4; r++) {
#pragma unroll
                for (int n = 0; n < 2; n++)
                    Hs[rbase + r][wave * 32 + n * 16 + frow] = f2bf(acc[m][n][r] + bb2[n]);
            }
        }
        __syncthreads();

        int nrows = min(64, NE - row0);
        int col = t & 255;
        int rs = (t >> 8) * 32;
        int re = min(nrows, rs + 32);
        if (rs < re) {
            float run = 0.f;
            int cur = Da[rs];
            for (int i = rs; i < re; ++i) {
                int d = Da[i];
                if (d != cur) {
                    atomicAdd(agg + (size_t)cur * 256 + col, run);
                    run = 0.f;
                    cur = d;
                }
                run += bf2f(Hs[i][col]);
            }
            atomicAdd(agg + (size_t)cur * 256 + col, run);
        }
    }
}

// ---------- GRU, bf16 MFMA v9: v8 + division-free fast gates ----------
__global__ __launch_bounds__(1024, 8) void k_gru_mfma(
    const float* __restrict__ agg, const unsigned short* __restrict__ membf,
    const float* __restrict__ counts,
    const unsigned short* __restrict__ pwih, const unsigned short* __restrict__ pwhh,
    const float* __restrict__ bih, const float* __restrict__ bhh,
    unsigned short* __restrict__ memout) {
    __shared__ unsigned short Af[2 * 2 * 8 * GPLANE];
    const int t = threadIdx.x;
    const int lane = t & 63, w = t >> 6;       // wave 0..15
    const int row0 = blockIdx.x * 32;
    const int frow = lane & 15, hi = lane >> 4;
    const int cqp = w >> 2;                     // 64-col block (0..3)
    const int ctl = w & 3;                      // 16-col frag within it

    // stage A once: 1024 threads x 8 floats = 32 rows x 256 cols
    {
        int sr = t >> 5, sq = t & 31;           // row 0..31, 8-float chunk 0..31
        int row = row0 + sr;
        float inv = 1.f / fmaxf(counts[row], 1.f);
        int k8 = sq * 8;
        int st = k8 >> 5, kq = (k8 >> 3) & 3;
        const float* pa = agg + (size_t)row * 256 + k8;
        const unsigned short* pm = membf + (size_t)row * 256 + k8;
        float4 a0 = *(const float4*)pa;
        float4 a1 = *(const float4*)(pa + 4);
        ushort8v um = *(const ushort8v*)pm;
        ushort8v ua;
        ua[0] = f2bf(a0.x * inv); ua[1] = f2bf(a0.y * inv); ua[2] = f2bf(a0.z * inv); ua[3] = f2bf(a0.w * inv);
        ua[4] = f2bf(a1.x * inv); ua[5] = f2bf(a1.y * inv); ua[6] = f2bf(a1.z * inv); ua[7] = f2bf(a1.w * inv);
        int smq = sr >> 4, sfr = sr & 15;
        int pos = kq * 16 + sfr;
        *(ushort8v*)&Af[(((0 * 2 + smq) * 8) + st) * GPLANE + pos * 8] = ua;
        *(ushort8v*)&Af[(((1 * 2 + smq) * 8) + st) * GPLANE + pos * 8] = um;
    }
    __syncthreads();

    f32x4 rpre[2], zpre[2], inn[2], hn[2];
#pragma unroll
    for (int mf = 0; mf < 2; ++mf) {
        rpre[mf] = (f32x4){0, 0, 0, 0};
        zpre[mf] = (f32x4){0, 0, 0, 0};
        inn[mf]  = (f32x4){0, 0, 0, 0};
        hn[mf]   = (f32x4){0, 0, 0, 0};
    }

    for (int step = 0; step < 8; ++step) {
        bf16x8 aA[2], aM[2];
#pragma unroll
        for (int mf = 0; mf < 2; ++mf) {
            aA[mf] = *(const bf16x8*)&Af[(((0 * 2 + mf) * 8) + step) * GPLANE + lane * 8];
            aM[mf] = *(const bf16x8*)&Af[(((1 * 2 + mf) * 8) + step) * GPLANE + lane * 8];
        }
        size_t o_r = (((size_t)step * 12 + 0 * 4 + cqp) * 4 + ctl) * 512 + lane * 8;
        size_t o_z = (((size_t)step * 12 + 1 * 4 + cqp) * 4 + ctl) * 512 + lane * 8;
        size_t o_n = (((size_t)step * 12 + 2 * 4 + cqp) * 4 + ctl) * 512 + lane * 8;
        bf16x8 bIr = *(const bf16x8*)(pwih + o_r);
        bf16x8 bHr = *(const bf16x8*)(pwhh + o_r);
        bf16x8 bIz = *(const bf16x8*)(pwih + o_z);
        bf16x8 bHz = *(const bf16x8*)(pwhh + o_z);
        bf16x8 bIn = *(const bf16x8*)(pwih + o_n);
        bf16x8 bHn = *(const bf16x8*)(pwhh + o_n);
#pragma unroll
        for (int mf = 0; mf < 2; ++mf) {
            rpre[mf] = __builtin_amdgcn_mfma_f32_16x16x32_bf16(aA[mf], bIr, rpre[mf], 0, 0, 0);
            rpre[mf] = __builtin_amdgcn_mfma_f32_16x16x32_bf16(aM[mf], bHr, rpre[mf], 0, 0, 0);
            zpre[mf] = __builtin_amdgcn_mfma_f32_16x16x32_bf16(aA[mf], bIz, zpre[mf], 0, 0, 0);
            zpre[mf] = __builtin_amdgcn_mfma_f32_16x16x32_bf16(aM[mf], bHz, zpre[mf], 0, 0, 0);
            inn[mf]  = __builtin_amdgcn_mfma_f32_16x16x32_bf16(aA[mf], bIn, inn[mf], 0, 0, 0);
            hn[mf]   = __builtin_amdgcn_mfma_f32_16x16x32_bf16(aM[mf], bHn, hn[mf], 0, 0, 0);
        }
    }

    const int col = cqp * 64 + ctl * 16 + frow;
    const float br = bih[col] + bhh[col];
    const float bz = bih[256 + col] + bhh[256 + col];
    const float bin = bih[512 + col];
    const float bhn = bhh[512 + col];
#pragma unroll
    for (int mf = 0; mf < 2; ++mf)
#pragma unroll
        for (int r = 0; r < 4; ++r) {
            int row = row0 + mf * 16 + hi * 4 + r;
            float cnt = counts[row];
            // division-free fast gates: sigmoid = rcp(1+exp(-x)),
            // tanh(y) = (1-t)*rcp(1+t), t = exp(-2*max(y,-44)) <= e^88 (finite)
            float er = __expf(-(rpre[mf][r] + br));
            float rg = __builtin_amdgcn_rcpf(1.f + er);
            float ez = __expf(-(zpre[mf][r] + bz));
            float zg = __builtin_amdgcn_rcpf(1.f + ez);
            float y = inn[mf][r] + bin + rg * (hn[mf][r] + bhn);
            float ty = __expf(-2.f * fmaxf(y, -44.f));
            float ng = (1.f - ty) * __builtin_amdgcn_rcpf(1.f + ty);
            int pos = ((col >> 3) & 3) * 16 + (hi * 4 + r);
            float hp = bf2f(Af[(((1 * 2 + mf) * 8) + (col >> 5)) * GPLANE + pos * 8 + (col & 7)]);
            memout[(size_t)row * 256 + col] = f2bf((cnt > 0.f) ? ((1.f - zg) * ng + zg * hp) : hp);
        }
}

// ---------- GAT xh GEMM + attention-logit fusion; bf16 input A ----------
__global__ __launch_bounds__(256, 4) void k_xh_mfma(
    const unsigned short* __restrict__ A, const unsigned short* __restrict__ wp,
    const float* __restrict__ asrc, const float* __restrict__ adst,
    unsigned short* __restrict__ xh, float* __restrict__ als, float* __restrict__ ald) {
    const int t = threadIdx.x;
    const int lane = t & 63, w = t >> 6;
    const int row0 = blockIdx.x * 64;
    const int frow = lane & 15, fk = (lane >> 4) * 8, hi = lane >> 4;

    f32x4 acc[4][4];
#pragma unroll
    for (int m = 0; m < 4; m++)
#pragma unroll
        for (int c = 0; c < 4; c++) acc[m][c] = (f32x4){0, 0, 0, 0};

    for (int step = 0; step < 8; ++step) {
        const int k0 = step * 32;
        bf16x8 a[4];
#pragma unroll
        for (int m = 0; m < 4; ++m) {
            int row = min(row0 + m * 16 + frow, NN - 1);
            a[m] = *(const bf16x8*)(A + (size_t)row * 256 + k0 + fk);
        }
#pragma unroll
        for (int ctl = 0; ctl < 4; ++ctl) {
            bf16x8 b = *(const bf16x8*)(wp + (((size_t)step * 4 + w) * 4 + ctl) * 512 + lane * 8);
#pragma unroll
            for (int m = 0; m < 4; ++m)
                acc[m][ctl] = __builtin_amdgcn_mfma_f32_16x16x32_bf16(a[m], b, acc[m][ctl], 0, 0, 0);
        }
    }

    float asv[4], adv[4];
#pragma unroll
    for (int ctl = 0; ctl < 4; ++ctl) {
        asv[ctl] = asrc[w * 64 + ctl * 16 + frow];
        adv[ctl] = adst[w * 64 + ctl * 16 + frow];
    }
#pragma unroll
    for (int m = 0; m < 4; ++m) {
        float ps[4] = {0, 0, 0, 0}, pd[4] = {0, 0, 0, 0};
#pragma unroll
        for (int ctl = 0; ctl < 4; ++ctl) {
            int col = w * 64 + ctl * 16 + frow;
#pragma unroll
            for (int r = 0; r < 4; ++r) {
                float v = acc[m][ctl][r];
                ps[r] += v * asv[ctl];
                pd[r] += v * adv[ctl];
                int row = row0 + m * 16 + hi * 4 + r;
                if (row < NN) xh[(size_t)row * 256 + col] = f2bf(v);
            }
        }
#pragma unroll
        for (int off = 1; off < 16; off <<= 1) {
#pragma unroll
            for (int r = 0; r < 4; ++r) {
                ps[r] += __shfl_xor(ps[r], off, 64);
                pd[r] += __shfl_xor(pd[r], off, 64);
            }
        }
        if (frow == 0) {
#pragma unroll
            for (int r = 0; r < 4; ++r) {
                int row = row0 + m * 16 + hi * 4 + r;
                if (row < NN) { als[row * 4 + w] = ps[r]; ald[row * 4 + w] = pd[r]; }
            }
        }
    }
}

// ---------- fused GAT edge-softmax + aggregate, CSR, single-pass ----------
// softmax without max-subtraction: logits are tiny (weights ~0.05), so
// exp(e) is far from fp32 range; exp(e)/sum == exp(e-m)/sum mathematically.
__global__ __launch_bounds__(256) void k_gat_csr(
    const int* __restrict__ rowptr, const int* __restrict__ colidx,
    const float* __restrict__ als, const float* __restrict__ ald,
    const unsigned short* __restrict__ xh, const float* __restrict__ bias,
    unsigned short* __restrict__ outb) {
    int d = blockIdx.x * 4 + (threadIdx.x >> 6);
    if (d >= NN) return;
    int lane = threadIdx.x & 63;
    int h = lane >> 4;
    int beg = rowptr[d], end = rowptr[d + 1];
    float aldv = ald[d * 4 + h];

    float den = 0.f;
    float a0 = 0.f, a1 = 0.f, a2 = 0.f, a3 = 0.f;
    for (int p = beg; p < end; ++p) {
        int s = colidx[p];
        float e = als[s * 4 + h] + aldv;
        e = e > 0.f ? e : 0.2f * e;
        float pw = __expf(e);
        den += pw;
        ushort4 uv = *(const ushort4*)(xh + (size_t)s * 256 + lane * 4);
        a0 += pw * bf2f(uv.x);
        a1 += pw * bf2f(uv.y);
        a2 += pw * bf2f(uv.z);
        a3 += pw * bf2f(uv.w);
    }
    float inv = 1.f / den;
    int c = lane * 4;
    float4 bv = *(const float4*)(bias + c);
    float ox = a0 * inv + bv.x; ox = ox > 0.f ? ox : expm1f(ox);
    float oy = a1 * inv + bv.y; oy = oy > 0.f ? oy : expm1f(oy);
    float oz = a2 * inv + bv.z; oz = oz > 0.f ? oz : expm1f(oz);
    float ow = a3 * inv + bv.w; ow = ow > 0.f ? ow : expm1f(ow);
    ushort4 o;
    o.x = f2bf(ox); o.y = f2bf(oy); o.z = f2bf(oz); o.w = f2bf(ow);
    *(ushort4*)(outb + (size_t)d * 256 + c) = o;
}

__global__ __launch_bounds__(256) void k_pool(const unsigned short* __restrict__ h,
                                              const int* __restrict__ batch, float* __restrict__ gsum) {
    int t = threadIdx.x;
    const int per = (NN + gridDim.x - 1) / gridDim.x;
    int n0 = blockIdx.x * per, n1 = min(NN, n0 + per);
    float s = 0.f, cnt = 0.f;
    for (int n = n0; n < n1; n++) {
        if (batch[n] == 0) {
            s += bf2f(h[(size_t)n * 256 + t]);
            cnt += 1.f;
        }
    }
    atomicAdd(&gsum[t], s);
    if (t == 0) atomicAdd(&gsum[256], cnt);
}

__global__ void k_cls(const float* __restrict__ gsum, const float* __restrict__ w1,
                      const float* __restrict__ b1, const float* __restrict__ w2,
                      const float* __restrict__ b2, float* __restrict__ out) {
    __shared__ float g[256];
    __shared__ float hid[128];
    int t = threadIdx.x;
    float gc = gsum[256];
    g[t] = gsum[t] / gc;
    __syncthreads();
    if (t < 128) {
        float s = b1[t];
        for (int k = 0; k < 256; k++) s += g[k] * w1[t * 256 + k];
        hid[t] = fmaxf(s, 0.f);
    }
    __syncthreads();
    if (t < 2) {
        float s = b2[t];
        for (int k = 0; k < 128; k++) s += hid[k] * w2[t * 128 + k];
        out[t] = s;
    }
}

// ---------- launch ----------
extern "C" void kernel_launch(void* const* d_in, const int* in_sizes, int n_in,
                              void* d_out, int out_size, void* d_ws, size_t ws_size,
                              hipStream_t stream) {
    const float* xv      = (const float*)d_in[0];
    const float* tsv     = (const float*)d_in[1];
    const float* nodemem = (const float*)d_in[2];
    const float* lut     = (const float*)d_in[3];
    const float* msg_w1  = (const float*)d_in[4];
    const float* msg_b1  = (const float*)d_in[5];
    const float* msg_w2  = (const float*)d_in[6];
    const float* msg_b2  = (const float*)d_in[7];
    const float* time_w1 = (const float*)d_in[8];
    const float* time_b1 = (const float*)d_in[9];
    const float* time_w2 = (const float*)d_in[10];
    const float* time_b2 = (const float*)d_in[11];
    const float* gru_wih = (const float*)d_in[12];
    const float* gru_whh = (const float*)d_in[13];
    const float* gru_bih = (const float*)d_in[14];
    const float* gru_bhh = (const float*)d_in[15];
    const float* gat1_w    = (const float*)d_in[16];
    const float* gat1_asrc = (const float*)d_in[17];
    const float* gat1_adst = (const float*)d_in[18];
    const float* gat1_b    = (const float*)d_in[19];
    const float* gat2_w    = (const float*)d_in[20];
    const float* gat2_asrc = (const float*)d_in[21];
    const float* gat2_adst = (const float*)d_in[22];
    const float* gat2_b    = (const float*)d_in[23];
    const float* cls_w1 = (const float*)d_in[24];
    const float* cls_b1 = (const float*)d_in[25];
    const float* cls_w2 = (const float*)d_in[26];
    const float* cls_b2 = (const float*)d_in[27];
    const int* ei    = (const int*)d_in[28];
    const int* batch = (const int*)d_in[29];
    float* out = (float*)d_out;

    char* wsb = (char*)d_ws;
    size_t off = 0;
    auto carve = [&](size_t bytes) {
        char* p = wsb + off;
        off += (bytes + 255) & ~(size_t)255;
        return p;
    };
    int*   curtime = (int*)carve(4);
    unsigned short* w1ap = (unsigned short*)carve((size_t)256 * 256 * 2);
    unsigned short* w1bp = (unsigned short*)carve((size_t)256 * 256 * 2);
    unsigned short* w1cp = (unsigned short*)carve((size_t)256 * 32 * 2);
    unsigned short* wtdp = (unsigned short*)carve((size_t)256 * 32 * 2);
    unsigned short* w2p  = (unsigned short*)carve((size_t)256 * 256 * 2);
    unsigned short* wihp = (unsigned short*)carve((size_t)768 * 256 * 2);
    unsigned short* whhp = (unsigned short*)carve((size_t)768 * 256 * 2);
    unsigned short* g1p  = (unsigned short*)carve((size_t)256 * 256 * 2);
    unsigned short* g2p  = (unsigned short*)carve((size_t)256 * 256 * 2);
    float* Mtd   = (float*)carve((size_t)256 * 32 * 4);
    float* b1eff = (float*)carve(256 * 4);
    unsigned short* P13  = (unsigned short*)carve((size_t)NN * 256 * 2);
    unsigned short* P2   = (unsigned short*)carve((size_t)NN * 256 * 2);
    unsigned short* membf = (unsigned short*)carve((size_t)NN * 256 * 2);
    float* als    = (float*)carve((size_t)NN * 4 * 4);
    float* ald    = (float*)carve((size_t)NN * 4 * 4);
    float* counts = (float*)carve((size_t)NN * 4);
    float* gsum   = (float*)carve(257 * 4);
    int*   rowptr = (int*)carve((size_t)(NN + 1) * 4);
    int*   colidx = (int*)carve((size_t)(NE + NN) * 4);
    int*   fillp  = (int*)carve((size_t)NN * 4);
    int*   bsum   = (int*)carve(512 * 4);
    int*   esrc   = (int*)carve((size_t)NE * 4);
    int*   edst   = (int*)carve((size_t)NE * 4);
    int*   fillE  = (int*)carve((size_t)NN * 4);
    float* R1     = (float*)carve((size_t)NN * 256 * 4);  // agg -> xh1(bf16) -> xh2(bf16)
    float* R2     = (float*)carve((size_t)NN * 256 * 4);  // memo/outb1/outb2 (bf16)

    if (ws_size < off) {
        k_dbg<<<1, 1, 0, stream>>>(out, (float)(ws_size >> 20));
        return;
    }

    float* agg   = R1;
    unsigned short* memo  = (unsigned short*)R2;
    unsigned short* xh1   = (unsigned short*)R1;
    unsigned short* xh2   = (unsigned short*)R1;
    unsigned short* outb1 = (unsigned short*)R2;
    unsigned short* outb2 = (unsigned short*)R2;

    // ---- init ----
    hipMemsetAsync(agg, 0, (size_t)NN * 256 * 4, stream);
    hipMemsetAsync(counts, 0, (size_t)NN * 4, stream);
    hipMemsetAsync(gsum, 0, 257 * 4, stream);
    k_fill_i32<<<1, 256, 0, stream>>>(curtime, (int)0x80000000, 1);

    // ---- weight prep: fold te weights, fragment-major packed bf16 ----
    k_fold_te<<<32, 256, 0, stream>>>(msg_w1, time_w2, time_b2, msg_b1, Mtd, b1eff);
    k_pack_w_sub<<<256, 256, 0, stream>>>(msg_w1, w1ap, 256, 256, 576, 0);
    k_pack_w_sub<<<256, 256, 0, stream>>>(msg_w1, w1bp, 256, 256, 576, 256);
    k_pack_w_sub<<<32, 256, 0, stream>>>(msg_w1, w1cp, 256, 32, 576, 512);
    k_pack_w_sub<<<32, 256, 0, stream>>>(Mtd, wtdp, 256, 32, 32, 0);
    k_pack_w_sub<<<256, 256, 0, stream>>>(msg_w2, w2p, 256, 256, 256, 0);
    k_pack_w_sub<<<768, 256, 0, stream>>>(gru_wih, wihp, 768, 256, 256, 0);
    k_pack_w_sub<<<768, 256, 0, stream>>>(gru_whh, whhp, 768, 256, 256, 0);
    k_pack_w_sub<<<256, 256, 0, stream>>>(gat1_w, g1p, 256, 256, 256, 0);
    k_pack_w_sub<<<256, 256, 0, stream>>>(gat2_w, g2p, 256, 256, 256, 0);

    // ---- counts + CSR build ----
    k_counts<<<1024, 256, 0, stream>>>(ei, counts);
    k_scan1<<<391, 256, 0, stream>>>(counts, rowptr, bsum);
    k_scan2<<<1, 512, 0, stream>>>(bsum, 391);
    k_scan3<<<391, 256, 0, stream>>>(rowptr, bsum, fillp, fillE);
    k_csr_fill<<<1563, 256, 0, stream>>>(ei, fillp, colidx);
    k_ecsr_fill<<<1172, 256, 0, stream>>>(ei, fillE, esrc, edst);

    // ---- per-node precompute + messages + memory update ----
    k_timemax<<<512, 256, 0, stream>>>(tsv, NE, curtime);
    k_pre1<<<3125, 512, 0, stream>>>(nodemem, xv, w1ap, w1bp, w1cp, P13, P2, membf);
    k_msg_mfma<<<4688, 512, 0, stream>>>(curtime, lut, esrc, edst, P13, P2,
                                         wtdp, b1eff, w2p, msg_b2,
                                         time_w1, time_b1, agg);
    k_gru_mfma<<<3125, 1024, 0, stream>>>(agg, membf, counts, wihp, whhp,
                                          gru_bih, gru_bhh, memo);

    // ---- GAT layer 1 ----
    k_xh_mfma<<<1563, 256, 0, stream>>>(memo, g1p, gat1_asrc, gat1_adst, xh1, als, ald);
    k_gat_csr<<<25000, 256, 0, stream>>>(rowptr, colidx, als, ald, xh1, gat1_b, outb1);

    // ---- GAT layer 2 ----
    k_xh_mfma<<<1563, 256, 0, stream>>>(outb1, g2p, gat2_asrc, gat2_adst, xh2, als, ald);
    k_gat_csr<<<25000, 256, 0, stream>>>(rowptr, colidx, als, ald, xh2, gat2_b, outb2);

    // ---- pool + classifier ----
    k_pool<<<2048, 256, 0, stream>>>(outb2, batch, gsum);
    k_cls<<<1, 256, 0, stream>>>(gsum, cls_w1, cls_b1, cls_w2, cls_b2, out);
}

// Round 27
// 742.456 us; speedup vs baseline: 1.0233x; 1.0233x over previous
//
#include <hip/hip_runtime.h>

#define NN 100000      // nodes
#define NE 300000      // edges
#define GPLANE 528     // shorts per LDS fragment plane (512 + 16 pad)

typedef float f32x4 __attribute__((ext_vector_type(4)));
typedef __bf16 bf16x8 __attribute__((ext_vector_type(8)));
typedef unsigned short ushort8v __attribute__((ext_vector_type(8)));

// ---------- helpers ----------
__device__ __forceinline__ int enc_f(float f) {
    int i = __float_as_int(f);
    return i >= 0 ? i : (i ^ 0x7fffffff);
}
__device__ __forceinline__ float dec_f(int i) {
    return __int_as_float(i >= 0 ? i : (i ^ 0x7fffffff));
}
__device__ __forceinline__ unsigned short f2bf(float f) {
    unsigned u = __float_as_uint(f);
    u += 0x7fffu + ((u >> 16) & 1u);
    return (unsigned short)(u >> 16);
}
__device__ __forceinline__ float bf2f(unsigned short u) {
    return __uint_as_float((unsigned)u << 16);
}

__global__ void k_dbg(float* out, float v) { out[0] = v; out[1] = v; }

__global__ void k_fill_i32(int* p, int v, int n) {
    int i = blockIdx.x * 256 + threadIdx.x;
    if (i < n) p[i] = v;
}

// pack W[o][off+k] (row stride `stride`) -> fragment-major bf16
__device__ __forceinline__ void pack_one(const float* __restrict__ src,
                                         unsigned short* __restrict__ dst,
                                         int OUT, int K, int stride, int off, int i) {
    int o = i / K, k = i % K;
    int ob = o >> 6, n = (o >> 4) & 3, fr = o & 15;
    int step = k >> 5, kq = (k >> 3) & 3, j = k & 7;
    size_t dsti = ((((size_t)step * (OUT >> 6) + ob) * 4 + n) * 64 + (kq * 16 + fr)) * 8 + j;
    dst[dsti] = f2bf(src[(size_t)o * stride + off + k]);
}

// all 9 weight packs in one launch (segment dispatch by global index)
__global__ void k_pack_all(const float* __restrict__ msg_w1, const float* __restrict__ Mtd,
                           const float* __restrict__ msg_w2,
                           const float* __restrict__ gru_wih, const float* __restrict__ gru_whh,
                           const float* __restrict__ gat1_w, const float* __restrict__ gat2_w,
                           unsigned short* __restrict__ w1ap, unsigned short* __restrict__ w1bp,
                           unsigned short* __restrict__ w1cp, unsigned short* __restrict__ wtdp,
                           unsigned short* __restrict__ w2p,
                           unsigned short* __restrict__ wihp, unsigned short* __restrict__ whhp,
                           unsigned short* __restrict__ g1p, unsigned short* __restrict__ g2p) {
    int i = blockIdx.x * 256 + threadIdx.x;
    if (i < 65536) { pack_one(msg_w1, w1ap, 256, 256, 576, 0, i); return; }
    i -= 65536;
    if (i < 65536) { pack_one(msg_w1, w1bp, 256, 256, 576, 256, i); return; }
    i -= 65536;
    if (i < 8192)  { pack_one(msg_w1, w1cp, 256, 32, 576, 512, i); return; }
    i -= 8192;
    if (i < 8192)  { pack_one(Mtd, wtdp, 256, 32, 32, 0, i); return; }
    i -= 8192;
    if (i < 65536) { pack_one(msg_w2, w2p, 256, 256, 256, 0, i); return; }
    i -= 65536;
    if (i < 196608) { pack_one(gru_wih, wihp, 768, 256, 256, 0, i); return; }
    i -= 196608;
    if (i < 196608) { pack_one(gru_whh, whhp, 768, 256, 256, 0, i); return; }
    i -= 196608;
    if (i < 65536) { pack_one(gat1_w, g1p, 256, 256, 256, 0, i); return; }
    i -= 65536;
    if (i < 65536) { pack_one(gat2_w, g2p, 256, 256, 256, 0, i); return; }
}

// Mtd[o][i] = sum_c W1d[o][c] * tw2[c][i] ; b1eff[o] = b1[o] + sum_c W1d[o][c]*tb2[c]
__global__ void k_fold_te(const float* __restrict__ msg_w1, const float* __restrict__ tw2,
                          const float* __restrict__ tb2, const float* __restrict__ b1,
                          float* __restrict__ Mtd, float* __restrict__ b1eff) {
    int i = blockIdx.x * 256 + threadIdx.x;
    if (i < 256 * 32) {
        int o = i >> 5, col = i & 31;
        float s = 0.f;
        const float* w1d = msg_w1 + (size_t)o * 576 + 544;
#pragma unroll
        for (int c = 0; c < 32; ++c) s += w1d[c] * tw2[c * 32 + col];
        Mtd[i] = s;
        if (col == 0) {
            float sb = b1[o];
#pragma unroll
            for (int c = 0; c < 32; ++c) sb += w1d[c] * tb2[c];
            b1eff[o] = sb;
        }
    }
}

__global__ void k_timemax(const float* __restrict__ ts, int n, int* out) {
    float m = -INFINITY;
    int stride = gridDim.x * blockDim.x;
    for (int i = blockIdx.x * blockDim.x + threadIdx.x; i < n; i += stride)
        m = fmaxf(m, ts[i]);
    atomicMax(out, enc_f(m));
}

__global__ void k_counts(const int* __restrict__ ei, float* __restrict__ counts) {
    int stride = gridDim.x * blockDim.x;
    for (int i = blockIdx.x * blockDim.x + threadIdx.x; i < NE; i += stride)
        atomicAdd(&counts[ei[NE + i]], 1.f);
}

// ---------- CSR build ----------
__global__ void k_scan1(const float* __restrict__ counts, int* __restrict__ rowptr,
                        int* __restrict__ bsum) {
    __shared__ int sh[256];
    int t = threadIdx.x;
    int i = blockIdx.x * 256 + t;
    int v = (i < NN) ? ((int)counts[i] + 1) : 0;
    sh[t] = v;
    __syncthreads();
    for (int off = 1; off < 256; off <<= 1) {
        int x = (t >= off) ? sh[t - off] : 0;
        __syncthreads();
        sh[t] += x;
        __syncthreads();
    }
    if (i < NN) rowptr[i + 1] = sh[t];
    if (t == 255) bsum[blockIdx.x] = sh[255];
}

__global__ void k_scan2(int* __restrict__ bsum, int nb) {
    __shared__ int sh[512];
    int t = threadIdx.x;
    sh[t] = (t < nb) ? bsum[t] : 0;
    __syncthreads();
    for (int off = 1; off < 512; off <<= 1) {
        int x = (t >= off) ? sh[t - off] : 0;
        __syncthreads();
        sh[t] += x;
        __syncthreads();
    }
    if (t < nb) bsum[t] = sh[t];
}

// finalize rowptr and seed both fill cursors (node CSR + edge-only list)
__global__ void k_scan3(int* __restrict__ rowptr, const int* __restrict__ bsum,
                        int* __restrict__ fillp, int* __restrict__ fillE) {
    int i = blockIdx.x * 256 + threadIdx.x;
    if (i == 0) {
        rowptr[0] = 0;
        fillp[0] = 0;
        fillE[0] = 0;
    }
    if (i < NN) {
        int b = i >> 8;
        int off = b > 0 ? bsum[b - 1] : 0;
        int v = rowptr[i + 1] + off;
        rowptr[i + 1] = v;
        if (i + 1 < NN) {
            fillp[i + 1] = v;
            fillE[i + 1] = v - (i + 1);
        }
    }
}

__global__ void k_csr_fill(const int* __restrict__ ei, int* __restrict__ fill,
                           int* __restrict__ colidx) {
    int i = blockIdx.x * 256 + threadIdx.x;
    if (i < NE) {
        int d = ei[NE + i];
        int pos = atomicAdd(&fill[d], 1);
        colidx[pos] = ei[i];
    } else if (i < NE + NN) {
        int n = i - NE;
        int pos = atomicAdd(&fill[n], 1);
        colidx[pos] = n;
    }
}

__global__ void k_ecsr_fill(const int* __restrict__ ei, int* __restrict__ fillE,
                            int* __restrict__ esrc, int* __restrict__ edst) {
    int i = blockIdx.x * 256 + threadIdx.x;
    if (i < NE) {
        int d = ei[NE + i];
        int pos = atomicAdd(&fillE[d], 1);
        esrc[pos] = ei[i];
        edst[pos] = d;
    }
}

// ---------- per-node precompute: P13/P2 + bf16 copy of mem (membf) ----------
__global__ __launch_bounds__(512, 4) void k_pre1(
    const float* __restrict__ mem, const float* __restrict__ x,
    const unsigned short* __restrict__ w1ap, const unsigned short* __restrict__ w1bp,
    const unsigned short* __restrict__ w1cp,
    unsigned short* __restrict__ P13, unsigned short* __restrict__ P2,
    unsigned short* __restrict__ membf) {
    __shared__ unsigned short Af[2 * 8 * GPLANE];
    __shared__ unsigned short Axf[2 * 512];
    const int t = threadIdx.x;
    const int lane = t & 63, w = t >> 6;
    const int row0 = blockIdx.x * 32;
    const int frow = lane & 15, hi = lane >> 4;
    const int half = w >> 2, cq = w & 3;

    {
        int sr = t >> 4, sq = t & 15;
        int row = row0 + sr;
        const float* pm = mem + (size_t)row * 256 + sq * 16;
        int smq = sr >> 4, sfr = sr & 15;
#pragma unroll
        for (int j2 = 0; j2 < 2; ++j2) {
            int k8 = sq * 16 + j2 * 8;
            int st = k8 >> 5, kq = (k8 >> 3) & 3;
            float4 m0 = *(const float4*)(pm + j2 * 8);
            float4 m1 = *(const float4*)(pm + j2 * 8 + 4);
            ushort8v um;
            um[0] = f2bf(m0.x); um[1] = f2bf(m0.y); um[2] = f2bf(m0.z); um[3] = f2bf(m0.w);
            um[4] = f2bf(m1.x); um[5] = f2bf(m1.y); um[6] = f2bf(m1.z); um[7] = f2bf(m1.w);
            *(ushort8v*)&Af[((smq * 8) + st) * GPLANE + (kq * 16 + sfr) * 8] = um;
            *(ushort8v*)(membf + (size_t)row * 256 + k8) = um;
        }
    }
    if (t < 128) {
        int sr = t >> 2, sq = t & 3;
        int row = row0 + sr;
        const float* px = x + (size_t)row * 32 + sq * 8;
        float4 v0 = *(const float4*)px, v1 = *(const float4*)(px + 4);
        ushort8v u;
        u[0] = f2bf(v0.x); u[1] = f2bf(v0.y); u[2] = f2bf(v0.z); u[3] = f2bf(v0.w);
        u[4] = f2bf(v1.x); u[5] = f2bf(v1.y); u[6] = f2bf(v1.z); u[7] = f2bf(v1.w);
        *(ushort8v*)&Axf[(sr >> 4) * 512 + (sq * 16 + (sr & 15)) * 8] = u;
    }
    __syncthreads();

    f32x4 acc[2][4];
#pragma unroll
    for (int mf = 0; mf < 2; ++mf)
#pragma unroll
        for (int c = 0; c < 4; ++c) acc[mf][c] = (f32x4){0, 0, 0, 0};

    const unsigned short* wp = half ? w1bp : w1ap;
    for (int step = 0; step < 8; ++step) {
        bf16x8 aA[2];
#pragma unroll
        for (int mf = 0; mf < 2; ++mf)
            aA[mf] = *(const bf16x8*)&Af[((mf * 8) + step) * GPLANE + lane * 8];
#pragma unroll
        for (int ctl = 0; ctl < 4; ++ctl) {
            bf16x8 b = *(const bf16x8*)(wp + (((size_t)step * 4 + cq) * 4 + ctl) * 512 + lane * 8);
#pragma unroll
            for (int mf = 0; mf < 2; ++mf)
                acc[mf][ctl] = __builtin_amdgcn_mfma_f32_16x16x32_bf16(aA[mf], b, acc[mf][ctl], 0, 0, 0);
        }
    }
    if (half == 0) {
        bf16x8 aX[2];
#pragma unroll
        for (int mf = 0; mf < 2; ++mf)
            aX[mf] = *(const bf16x8*)&Axf[mf * 512 + lane * 8];
#pragma unroll
        for (int ctl = 0; ctl < 4; ++ctl) {
            bf16x8 b = *(const bf16x8*)(w1cp + (((size_t)0 * 4 + cq) * 4 + ctl) * 512 + lane * 8);
#pragma unroll
            for (int mf = 0; mf < 2; ++mf)
                acc[mf][ctl] = __builtin_amdgcn_mfma_f32_16x16x32_bf16(aX[mf], b, acc[mf][ctl], 0, 0, 0);
        }
    }
    unsigned short* P = half ? P2 : P13;
#pragma unroll
    for (int mf = 0; mf < 2; ++mf)
#pragma unroll
        for (int ctl = 0; ctl < 4; ++ctl) {
            int col = cq * 64 + ctl * 16 + frow;
#pragma unroll
            for (int r = 0; r < 4; ++r) {
                int row = row0 + mf * 16 + hi * 4 + r;
                P[(size_t)row * 256 + col] = f2bf(acc[mf][ctl][r]);
            }
        }
}

// ---------- edge message kernel, 512 thr (8 waves x 64x32 out) ----------
__global__ __launch_bounds__(512, 4) void k_msg_mfma(
    const int* __restrict__ ct, const float* __restrict__ lut,
    const int* __restrict__ esrc, const int* __restrict__ edst,
    const unsigned short* __restrict__ P13, const unsigned short* __restrict__ P2,
    const unsigned short* __restrict__ wtdp, const float* __restrict__ b1eff,
    const unsigned short* __restrict__ w2p, const float* __restrict__ b2,
    const float* __restrict__ tw1, const float* __restrict__ tb1,
    float* __restrict__ agg) {
    __shared__ unsigned short As[64][40];
    __shared__ unsigned short Hs[64][264];
    __shared__ int Da[64];

    const int t = threadIdx.x;
    const int lane = t & 63, wave = t >> 6;
    const int row0 = blockIdx.x * 64;
    const int frow = lane & 15;
    const int fk = (lane >> 4) * 8;
    const int hi = lane >> 4;
    const int wb = wave >> 1;
    const int wn = (wave & 1) * 2;

    if (t < 64) {
        int e = row0 + t;
        Da[t] = (e < NE) ? edst[e] : -1;
    }

    const int srow = t >> 3;
    const int sj = t & 7;
    const int eIdx = row0 + srow;
    const bool ev = eIdx < NE;
    const int s_e = ev ? esrc[eIdx] : 0;
    const int d_e = ev ? edst[eIdx] : 0;

    {
        float ctv = dec_f(*ct);
        float dt = ev ? (ctv - fmaxf(lut[s_e], lut[d_e])) : 0.f;
        ushort4 u;
        int c0 = sj * 4;
        u.x = f2bf(fmaxf(dt * tw1[c0 + 0] + tb1[c0 + 0], 0.f));
        u.y = f2bf(fmaxf(dt * tw1[c0 + 1] + tb1[c0 + 1], 0.f));
        u.z = f2bf(fmaxf(dt * tw1[c0 + 2] + tb1[c0 + 2], 0.f));
        u.w = f2bf(fmaxf(dt * tw1[c0 + 3] + tb1[c0 + 3], 0.f));
        *(ushort4*)&As[srow][c0] = u;
    }
#pragma unroll
    for (int q = 0; q < 4; ++q) {
        int c = sj * 8 + q * 64;
        ushort4 a0 = *(const ushort4*)(P13 + (size_t)s_e * 256 + c);
        ushort4 a1 = *(const ushort4*)(P13 + (size_t)s_e * 256 + c + 4);
        ushort4 b0 = *(const ushort4*)(P2 + (size_t)d_e * 256 + c);
        ushort4 b1v = *(const ushort4*)(P2 + (size_t)d_e * 256 + c + 4);
        ushort8v u;
        u[0] = f2bf(bf2f(a0.x) + bf2f(b0.x)); u[1] = f2bf(bf2f(a0.y) + bf2f(b0.y));
        u[2] = f2bf(bf2f(a0.z) + bf2f(b0.z)); u[3] = f2bf(bf2f(a0.w) + bf2f(b0.w));
        u[4] = f2bf(bf2f(a1.x) + bf2f(b1v.x)); u[5] = f2bf(bf2f(a1.y) + bf2f(b1v.y));
        u[6] = f2bf(bf2f(a1.z) + bf2f(b1v.z)); u[7] = f2bf(bf2f(a1.w) + bf2f(b1v.w));
        *(ushort8v*)&Hs[srow][c] = u;
    }
    __syncthreads();

    f32x4 acc[4][2];
#pragma unroll
    for (int m = 0; m < 4; m++)
#pragma unroll
        for (int n = 0; n < 2; n++) acc[m][n] = (f32x4){0.f, 0.f, 0.f, 0.f};

    {
        bf16x8 a[4];
#pragma unroll
        for (int m = 0; m < 4; m++)
            a[m] = *(const bf16x8*)&As[m * 16 + frow][fk];
#pragma unroll
        for (int n = 0; n < 2; n++) {
            bf16x8 b = *(const bf16x8*)(wtdp + (((size_t)0 * 4 + wb) * 4 + (wn + n)) * 512 + lane * 8);
#pragma unroll
            for (int m = 0; m < 4; m++)
                acc[m][n] = __builtin_amdgcn_mfma_f32_16x16x32_bf16(a[m], b, acc[m][n], 0, 0, 0);
        }
    }
#pragma unroll
    for (int n = 0; n < 2; n++) {
        int c = wave * 32 + n * 16 + frow;
        float bb = b1eff[c];
#pragma unroll
        for (int m = 0; m < 4; m++) {
#pragma unroll
            for (int r = 0; r < 4; r++) {
                int rr = m * 16 + hi * 4 + r;
                float v = acc[m][n][r] + bf2f(Hs[rr][c]) + bb;
                Hs[rr][c] = f2bf(fmaxf(v, 0.f));
            }
            acc[m][n] = (f32x4){0.f, 0.f, 0.f, 0.f};
        }
    }
    __syncthreads();

    bf16x8 bnext[2];
#pragma unroll
    for (int n = 0; n < 2; n++)
        bnext[n] = *(const bf16x8*)(w2p + (((size_t)0 * 4 + wb) * 4 + (wn + n)) * 512 + lane * 8);
    for (int step = 0; step < 8; ++step) {
        const int k0 = step * 32;
        bf16x8 bcur[2];
#pragma unroll
        for (int n = 0; n < 2; n++) bcur[n] = bnext[n];
        if (step < 7) {
#pragma unroll
            for (int n = 0; n < 2; n++)
                bnext[n] = *(const bf16x8*)(w2p + (((size_t)(step + 1) * 4 + wb) * 4 + (wn + n)) * 512 + lane * 8);
        }
        bf16x8 a[4];
#pragma unroll
        for (int m = 0; m < 4; m++)
            a[m] = *(const bf16x8*)&Hs[m * 16 + frow][k0 + fk];
#pragma unroll
        for (int m = 0; m < 4; m++)
#pragma unroll
            for (int n = 0; n < 2; n++)
                acc[m][n] = __builtin_amdgcn_mfma_f32_16x16x32_bf16(a[m], bcur[n], acc[m][n], 0, 0, 0);
    }

    __syncthreads();
    {
        float bb2[2];
#pragma unroll
        for (int n = 0; n < 2; n++) bb2[n] = b2[wave * 32 + n * 16 + frow];
#pragma unroll
        for (int m = 0; m < 4; m++) {
            int rbase = m * 16 + hi * 4;
#pragma unroll
            for (int r = 0; r < 4; r++) {
#pragma unroll
                for (int n = 0; n < 2; n++)
                    Hs[rbase + r][wave * 32 + n * 16 + frow] = f2bf(acc[m][n][r] + bb2[n]);
            }
        }
        __syncthreads();

        int nrows = min(64, NE - row0);
        int col = t & 255;
        int rs = (t >> 8) * 32;
        int re = min(nrows, rs + 32);
        if (rs < re) {
            float run = 0.f;
            int cur = Da[rs];
            for (int i = rs; i < re; ++i) {
                int d = Da[i];
                if (d != cur) {
                    atomicAdd(agg + (size_t)cur * 256 + col, run);
                    run = 0.f;
                    cur = d;
                }
                run += bf2f(Hs[i][col]);
            }
            atomicAdd(agg + (size_t)cur * 256 + col, run);
        }
    }
}

// ---------- GRU, bf16 MFMA v9: v8 + division-free fast gates ----------
__global__ __launch_bounds__(1024, 8) void k_gru_mfma(
    const float* __restrict__ agg, const unsigned short* __restrict__ membf,
    const float* __restrict__ counts,
    const unsigned short* __restrict__ pwih, const unsigned short* __restrict__ pwhh,
    const float* __restrict__ bih, const float* __restrict__ bhh,
    unsigned short* __restrict__ memout) {
    __shared__ unsigned short Af[2 * 2 * 8 * GPLANE];
    const int t = threadIdx.x;
    const int lane = t & 63, w = t >> 6;       // wave 0..15
    const int row0 = blockIdx.x * 32;
    const int frow = lane & 15, hi = lane >> 4;
    const int cqp = w >> 2;                     // 64-col block (0..3)
    const int ctl = w & 3;                      // 16-col frag within it

    // stage A once: 1024 threads x 8 floats = 32 rows x 256 cols
    {
        int sr = t >> 5, sq = t & 31;           // row 0..31, 8-float chunk 0..31
        int row = row0 + sr;
        float inv = 1.f / fmaxf(counts[row], 1.f);
        int k8 = sq * 8;
        int st = k8 >> 5, kq = (k8 >> 3) & 3;
        const float* pa = agg + (size_t)row * 256 + k8;
        const unsigned short* pm = membf + (size_t)row * 256 + k8;
        float4 a0 = *(const float4*)pa;
        float4 a1 = *(const float4*)(pa + 4);
        ushort8v um = *(const ushort8v*)pm;
        ushort8v ua;
        ua[0] = f2bf(a0.x * inv); ua[1] = f2bf(a0.y * inv); ua[2] = f2bf(a0.z * inv); ua[3] = f2bf(a0.w * inv);
        ua[4] = f2bf(a1.x * inv); ua[5] = f2bf(a1.y * inv); ua[6] = f2bf(a1.z * inv); ua[7] = f2bf(a1.w * inv);
        int smq = sr >> 4, sfr = sr & 15;
        int pos = kq * 16 + sfr;
        *(ushort8v*)&Af[(((0 * 2 + smq) * 8) + st) * GPLANE + pos * 8] = ua;
        *(ushort8v*)&Af[(((1 * 2 + smq) * 8) + st) * GPLANE + pos * 8] = um;
    }
    __syncthreads();

    f32x4 rpre[2], zpre[2], inn[2], hn[2];
#pragma unroll
    for (int mf = 0; mf < 2; ++mf) {
        rpre[mf] = (f32x4){0, 0, 0, 0};
        zpre[mf] = (f32x4){0, 0, 0, 0};
        inn[mf]  = (f32x4){0, 0, 0, 0};
        hn[mf]   = (f32x4){0, 0, 0, 0};
    }

    for (int step = 0; step < 8; ++step) {
        bf16x8 aA[2], aM[2];
#pragma unroll
        for (int mf = 0; mf < 2; ++mf) {
            aA[mf] = *(const bf16x8*)&Af[(((0 * 2 + mf) * 8) + step) * GPLANE + lane * 8];
            aM[mf] = *(const bf16x8*)&Af[(((1 * 2 + mf) * 8) + step) * GPLANE + lane * 8];
        }
        size_t o_r = (((size_t)step * 12 + 0 * 4 + cqp) * 4 + ctl) * 512 + lane * 8;
        size_t o_z = (((size_t)step * 12 + 1 * 4 + cqp) * 4 + ctl) * 512 + lane * 8;
        size_t o_n = (((size_t)step * 12 + 2 * 4 + cqp) * 4 + ctl) * 512 + lane * 8;
        bf16x8 bIr = *(const bf16x8*)(pwih + o_r);
        bf16x8 bHr = *(const bf16x8*)(pwhh + o_r);
        bf16x8 bIz = *(const bf16x8*)(pwih + o_z);
        bf16x8 bHz = *(const bf16x8*)(pwhh + o_z);
        bf16x8 bIn = *(const bf16x8*)(pwih + o_n);
        bf16x8 bHn = *(const bf16x8*)(pwhh + o_n);
#pragma unroll
        for (int mf = 0; mf < 2; ++mf) {
            rpre[mf] = __builtin_amdgcn_mfma_f32_16x16x32_bf16(aA[mf], bIr, rpre[mf], 0, 0, 0);
            rpre[mf] = __builtin_amdgcn_mfma_f32_16x16x32_bf16(aM[mf], bHr, rpre[mf], 0, 0, 0);
            zpre[mf] = __builtin_amdgcn_mfma_f32_16x16x32_bf16(aA[mf], bIz, zpre[mf], 0, 0, 0);
            zpre[mf] = __builtin_amdgcn_mfma_f32_16x16x32_bf16(aM[mf], bHz, zpre[mf], 0, 0, 0);
            inn[mf]  = __builtin_amdgcn_mfma_f32_16x16x32_bf16(aA[mf], bIn, inn[mf], 0, 0, 0);
            hn[mf]   = __builtin_amdgcn_mfma_f32_16x16x32_bf16(aM[mf], bHn, hn[mf], 0, 0, 0);
        }
    }

    const int col = cqp * 64 + ctl * 16 + frow;
    const float br = bih[col] + bhh[col];
    const float bz = bih[256 + col] + bhh[256 + col];
    const float bin = bih[512 + col];
    const float bhn = bhh[512 + col];
#pragma unroll
    for (int mf = 0; mf < 2; ++mf)
#pragma unroll
        for (int r = 0; r < 4; ++r) {
            int row = row0 + mf * 16 + hi * 4 + r;
            float cnt = counts[row];
            // division-free fast gates: sigmoid = rcp(1+exp(-x)),
            // tanh(y) = (1-t)*rcp(1+t), t = exp(-2*max(y,-44)) <= e^88 (finite)
            float er = __expf(-(rpre[mf][r] + br));
            float rg = __builtin_amdgcn_rcpf(1.f + er);
            float ez = __expf(-(zpre[mf][r] + bz));
            float zg = __builtin_amdgcn_rcpf(1.f + ez);
            float y = inn[mf][r] + bin + rg * (hn[mf][r] + bhn);
            float ty = __expf(-2.f * fmaxf(y, -44.f));
            float ng = (1.f - ty) * __builtin_amdgcn_rcpf(1.f + ty);
            int pos = ((col >> 3) & 3) * 16 + (hi * 4 + r);
            float hp = bf2f(Af[(((1 * 2 + mf) * 8) + (col >> 5)) * GPLANE + pos * 8 + (col & 7)]);
            memout[(size_t)row * 256 + col] = f2bf((cnt > 0.f) ? ((1.f - zg) * ng + zg * hp) : hp);
        }
}

// ---------- GAT xh GEMM + attention-logit fusion; bf16 input A ----------
__global__ __launch_bounds__(256, 4) void k_xh_mfma(
    const unsigned short* __restrict__ A, const unsigned short* __restrict__ wp,
    const float* __restrict__ asrc, const float* __restrict__ adst,
    unsigned short* __restrict__ xh, float* __restrict__ als, float* __restrict__ ald) {
    const int t = threadIdx.x;
    const int lane = t & 63, w = t >> 6;
    const int row0 = blockIdx.x * 64;
    const int frow = lane & 15, fk = (lane >> 4) * 8, hi = lane >> 4;

    f32x4 acc[4][4];
#pragma unroll
    for (int m = 0; m < 4; m++)
#pragma unroll
        for (int c = 0; c < 4; c++) acc[m][c] = (f32x4){0, 0, 0, 0};

    for (int step = 0; step < 8; ++step) {
        const int k0 = step * 32;
        bf16x8 a[4];
#pragma unroll
        for (int m = 0; m < 4; ++m) {
            int row = min(row0 + m * 16 + frow, NN - 1);
            a[m] = *(const bf16x8*)(A + (size_t)row * 256 + k0 + fk);
        }
#pragma unroll
        for (int ctl = 0; ctl < 4; ++ctl) {
            bf16x8 b = *(const bf16x8*)(wp + (((size_t)step * 4 + w) * 4 + ctl) * 512 + lane * 8);
#pragma unroll
            for (int m = 0; m < 4; ++m)
                acc[m][ctl] = __builtin_amdgcn_mfma_f32_16x16x32_bf16(a[m], b, acc[m][ctl], 0, 0, 0);
        }
    }

    float asv[4], adv[4];
#pragma unroll
    for (int ctl = 0; ctl < 4; ++ctl) {
        asv[ctl] = asrc[w * 64 + ctl * 16 + frow];
        adv[ctl] = adst[w * 64 + ctl * 16 + frow];
    }
#pragma unroll
    for (int m = 0; m < 4; ++m) {
        float ps[4] = {0, 0, 0, 0}, pd[4] = {0, 0, 0, 0};
#pragma unroll
        for (int ctl = 0; ctl < 4; ++ctl) {
            int col = w * 64 + ctl * 16 + frow;
#pragma unroll
            for (int r = 0; r < 4; ++r) {
                float v = acc[m][ctl][r];
                ps[r] += v * asv[ctl];
                pd[r] += v * adv[ctl];
                int row = row0 + m * 16 + hi * 4 + r;
                if (row < NN) xh[(size_t)row * 256 + col] = f2bf(v);
            }
        }
#pragma unroll
        for (int off = 1; off < 16; off <<= 1) {
#pragma unroll
            for (int r = 0; r < 4; ++r) {
                ps[r] += __shfl_xor(ps[r], off, 64);
                pd[r] += __shfl_xor(pd[r], off, 64);
            }
        }
        if (frow == 0) {
#pragma unroll
            for (int r = 0; r < 4; ++r) {
                int row = row0 + m * 16 + hi * 4 + r;
                if (row < NN) { als[row * 4 + w] = ps[r]; ald[row * 4 + w] = pd[r]; }
            }
        }
    }
}

// ---------- fused GAT edge-softmax + aggregate, CSR, single-pass ----------
__global__ __launch_bounds__(256) void k_gat_csr(
    const int* __restrict__ rowptr, const int* __restrict__ colidx,
    const float* __restrict__ als, const float* __restrict__ ald,
    const unsigned short* __restrict__ xh, const float* __restrict__ bias,
    unsigned short* __restrict__ outb) {
    int d = blockIdx.x * 4 + (threadIdx.x >> 6);
    if (d >= NN) return;
    int lane = threadIdx.x & 63;
    int h = lane >> 4;
    int beg = rowptr[d], end = rowptr[d + 1];
    float aldv = ald[d * 4 + h];

    float den = 0.f;
    float a0 = 0.f, a1 = 0.f, a2 = 0.f, a3 = 0.f;
    for (int p = beg; p < end; ++p) {
        int s = colidx[p];
        float e = als[s * 4 + h] + aldv;
        e = e > 0.f ? e : 0.2f * e;
        float pw = __expf(e);
        den += pw;
        ushort4 uv = *(const ushort4*)(xh + (size_t)s * 256 + lane * 4);
        a0 += pw * bf2f(uv.x);
        a1 += pw * bf2f(uv.y);
        a2 += pw * bf2f(uv.z);
        a3 += pw * bf2f(uv.w);
    }
    float inv = 1.f / den;
    int c = lane * 4;
    float4 bv = *(const float4*)(bias + c);
    float ox = a0 * inv + bv.x; ox = ox > 0.f ? ox : expm1f(ox);
    float oy = a1 * inv + bv.y; oy = oy > 0.f ? oy : expm1f(oy);
    float oz = a2 * inv + bv.z; oz = oz > 0.f ? oz : expm1f(oz);
    float ow = a3 * inv + bv.w; ow = ow > 0.f ? ow : expm1f(ow);
    ushort4 o;
    o.x = f2bf(ox); o.y = f2bf(oy); o.z = f2bf(oz); o.w = f2bf(ow);
    *(ushort4*)(outb + (size_t)d * 256 + c) = o;
}

__global__ __launch_bounds__(256) void k_pool(const unsigned short* __restrict__ h,
                                              const int* __restrict__ batch, float* __restrict__ gsum) {
    int t = threadIdx.x;
    const int per = (NN + gridDim.x - 1) / gridDim.x;
    int n0 = blockIdx.x * per, n1 = min(NN, n0 + per);
    float s = 0.f, cnt = 0.f;
    for (int n = n0; n < n1; n++) {
        if (batch[n] == 0) {
            s += bf2f(h[(size_t)n * 256 + t]);
            cnt += 1.f;
        }
    }
    atomicAdd(&gsum[t], s);
    if (t == 0) atomicAdd(&gsum[256], cnt);
}

__global__ void k_cls(const float* __restrict__ gsum, const float* __restrict__ w1,
                      const float* __restrict__ b1, const float* __restrict__ w2,
                      const float* __restrict__ b2, float* __restrict__ out) {
    __shared__ float g[256];
    __shared__ float hid[128];
    int t = threadIdx.x;
    float gc = gsum[256];
    g[t] = gsum[t] / gc;
    __syncthreads();
    if (t < 128) {
        float s = b1[t];
        for (int k = 0; k < 256; k++) s += g[k] * w1[t * 256 + k];
        hid[t] = fmaxf(s, 0.f);
    }
    __syncthreads();
    if (t < 2) {
        float s = b2[t];
        for (int k = 0; k < 128; k++) s += hid[k] * w2[t * 128 + k];
        out[t] = s;
    }
}

// ---------- launch ----------
extern "C" void kernel_launch(void* const* d_in, const int* in_sizes, int n_in,
                              void* d_out, int out_size, void* d_ws, size_t ws_size,
                              hipStream_t stream) {
    const float* xv      = (const float*)d_in[0];
    const float* tsv     = (const float*)d_in[1];
    const float* nodemem = (const float*)d_in[2];
    const float* lut     = (const float*)d_in[3];
    const float* msg_w1  = (const float*)d_in[4];
    const float* msg_b1  = (const float*)d_in[5];
    const float* msg_w2  = (const float*)d_in[6];
    const float* msg_b2  = (const float*)d_in[7];
    const float* time_w1 = (const float*)d_in[8];
    const float* time_b1 = (const float*)d_in[9];
    const float* time_w2 = (const float*)d_in[10];
    const float* time_b2 = (const float*)d_in[11];
    const float* gru_wih = (const float*)d_in[12];
    const float* gru_whh = (const float*)d_in[13];
    const float* gru_bih = (const float*)d_in[14];
    const float* gru_bhh = (const float*)d_in[15];
    const float* gat1_w    = (const float*)d_in[16];
    const float* gat1_asrc = (const float*)d_in[17];
    const float* gat1_adst = (const float*)d_in[18];
    const float* gat1_b    = (const float*)d_in[19];
    const float* gat2_w    = (const float*)d_in[20];
    const float* gat2_asrc = (const float*)d_in[21];
    const float* gat2_adst = (const float*)d_in[22];
    const float* gat2_b    = (const float*)d_in[23];
    const float* cls_w1 = (const float*)d_in[24];
    const float* cls_b1 = (const float*)d_in[25];
    const float* cls_w2 = (const float*)d_in[26];
    const float* cls_b2 = (const float*)d_in[27];
    const int* ei    = (const int*)d_in[28];
    const int* batch = (const int*)d_in[29];
    float* out = (float*)d_out;

    char* wsb = (char*)d_ws;
    size_t off = 0;
    auto carve = [&](size_t bytes) {
        char* p = wsb + off;
        off += (bytes + 255) & ~(size_t)255;
        return p;
    };
    int*   curtime = (int*)carve(4);
    unsigned short* w1ap = (unsigned short*)carve((size_t)256 * 256 * 2);
    unsigned short* w1bp = (unsigned short*)carve((size_t)256 * 256 * 2);
    unsigned short* w1cp = (unsigned short*)carve((size_t)256 * 32 * 2);
    unsigned short* wtdp = (unsigned short*)carve((size_t)256 * 32 * 2);
    unsigned short* w2p  = (unsigned short*)carve((size_t)256 * 256 * 2);
    unsigned short* wihp = (unsigned short*)carve((size_t)768 * 256 * 2);
    unsigned short* whhp = (unsigned short*)carve((size_t)768 * 256 * 2);
    unsigned short* g1p  = (unsigned short*)carve((size_t)256 * 256 * 2);
    unsigned short* g2p  = (unsigned short*)carve((size_t)256 * 256 * 2);
    float* Mtd   = (float*)carve((size_t)256 * 32 * 4);
    float* b1eff = (float*)carve(256 * 4);
    unsigned short* P13  = (unsigned short*)carve((size_t)NN * 256 * 2);
    unsigned short* P2   = (unsigned short*)carve((size_t)NN * 256 * 2);
    unsigned short* membf = (unsigned short*)carve((size_t)NN * 256 * 2);
    float* als    = (float*)carve((size_t)NN * 4 * 4);
    float* ald    = (float*)carve((size_t)NN * 4 * 4);
    float* counts = (float*)carve((size_t)NN * 4);
    float* gsum   = (float*)carve(257 * 4);
    int*   rowptr = (int*)carve((size_t)(NN + 1) * 4);
    int*   colidx = (int*)carve((size_t)(NE + NN) * 4);
    int*   fillp  = (int*)carve((size_t)NN * 4);
    int*   bsum   = (int*)carve(512 * 4);
    int*   esrc   = (int*)carve((size_t)NE * 4);
    int*   edst   = (int*)carve((size_t)NE * 4);
    int*   fillE  = (int*)carve((size_t)NN * 4);
    float* R1     = (float*)carve((size_t)NN * 256 * 4);  // agg -> xh1(bf16) -> xh2(bf16)
    float* R2     = (float*)carve((size_t)NN * 256 * 4);  // memo/outb1/outb2 (bf16)

    if (ws_size < off) {
        k_dbg<<<1, 1, 0, stream>>>(out, (float)(ws_size >> 20));
        return;
    }

    float* agg   = R1;
    unsigned short* memo  = (unsigned short*)R2;
    unsigned short* xh1   = (unsigned short*)R1;
    unsigned short* xh2   = (unsigned short*)R1;
    unsigned short* outb1 = (unsigned short*)R2;
    unsigned short* outb2 = (unsigned short*)R2;

    // ---- init ----
    hipMemsetAsync(agg, 0, (size_t)NN * 256 * 4, stream);
    hipMemsetAsync(counts, 0, (size_t)NN * 4, stream);
    hipMemsetAsync(gsum, 0, 257 * 4, stream);
    k_fill_i32<<<1, 256, 0, stream>>>(curtime, (int)0x80000000, 1);

    // ---- weight prep: fold te weights, then ALL packs in one launch ----
    k_fold_te<<<32, 256, 0, stream>>>(msg_w1, time_w2, time_b2, msg_b1, Mtd, b1eff);
    k_pack_all<<<2880, 256, 0, stream>>>(msg_w1, Mtd, msg_w2, gru_wih, gru_whh,
                                         gat1_w, gat2_w,
                                         w1ap, w1bp, w1cp, wtdp, w2p,
                                         wihp, whhp, g1p, g2p);

    // ---- counts + CSR build ----
    k_counts<<<1024, 256, 0, stream>>>(ei, counts);
    k_scan1<<<391, 256, 0, stream>>>(counts, rowptr, bsum);
    k_scan2<<<1, 512, 0, stream>>>(bsum, 391);
    k_scan3<<<391, 256, 0, stream>>>(rowptr, bsum, fillp, fillE);
    k_csr_fill<<<1563, 256, 0, stream>>>(ei, fillp, colidx);
    k_ecsr_fill<<<1172, 256, 0, stream>>>(ei, fillE, esrc, edst);

    // ---- per-node precompute + messages + memory update ----
    k_timemax<<<512, 256, 0, stream>>>(tsv, NE, curtime);
    k_pre1<<<3125, 512, 0, stream>>>(nodemem, xv, w1ap, w1bp, w1cp, P13, P2, membf);
    k_msg_mfma<<<4688, 512, 0, stream>>>(curtime, lut, esrc, edst, P13, P2,
                                         wtdp, b1eff, w2p, msg_b2,
                                         time_w1, time_b1, agg);
    k_gru_mfma<<<3125, 1024, 0, stream>>>(agg, membf, counts, wihp, whhp,
                                          gru_bih, gru_bhh, memo);

    // ---- GAT layer 1 ----
    k_xh_mfma<<<1563, 256, 0, stream>>>(memo, g1p, gat1_asrc, gat1_adst, xh1, als, ald);
    k_gat_csr<<<25000, 256, 0, stream>>>(rowptr, colidx, als, ald, xh1, gat1_b, outb1);

    // ---- GAT layer 2 ----
    k_xh_mfma<<<1563, 256, 0, stream>>>(outb1, g2p, gat2_asrc, gat2_adst, xh2, als, ald);
    k_gat_csr<<<25000, 256, 0, stream>>>(rowptr, colidx, als, ald, xh2, gat2_b, outb2);

    // ---- pool + classifier ----
    k_pool<<<2048, 256, 0, stream>>>(outb2, batch, gsum);
    k_cls<<<1, 256, 0, stream>>>(gsum, cls_w1, cls_b1, cls_w2, cls_b2, out);
}

// Round 28
// 719.917 us; speedup vs baseline: 1.0553x; 1.0313x over previous
//
#include <hip/hip_runtime.h>

#define NN 100000      // nodes
#define NE 300000      // edges
#define GPLANE 528     // shorts per LDS fragment plane (512 + 16 pad)

typedef float f32x4 __attribute__((ext_vector_type(4)));
typedef __bf16 bf16x8 __attribute__((ext_vector_type(8)));
typedef unsigned short ushort8v __attribute__((ext_vector_type(8)));

// ---------- helpers ----------
__device__ __forceinline__ int enc_f(float f) {
    int i = __float_as_int(f);
    return i >= 0 ? i : (i ^ 0x7fffffff);
}
__device__ __forceinline__ float dec_f(int i) {
    return __int_as_float(i >= 0 ? i : (i ^ 0x7fffffff));
}
__device__ __forceinline__ unsigned short f2bf(float f) {
    unsigned u = __float_as_uint(f);
    u += 0x7fffu + ((u >> 16) & 1u);
    return (unsigned short)(u >> 16);
}
__device__ __forceinline__ float bf2f(unsigned short u) {
    return __uint_as_float((unsigned)u << 16);
}

__global__ void k_dbg(float* out, float v) { out[0] = v; out[1] = v; }

__global__ void k_fill_i32(int* p, int v, int n) {
    int i = blockIdx.x * 256 + threadIdx.x;
    if (i < n) p[i] = v;
}

// pack W[o][off+k] (row stride `stride`) -> fragment-major bf16
__device__ __forceinline__ void pack_one(const float* __restrict__ src,
                                         unsigned short* __restrict__ dst,
                                         int OUT, int K, int stride, int off, int i) {
    int o = i / K, k = i % K;
    int ob = o >> 6, n = (o >> 4) & 3, fr = o & 15;
    int step = k >> 5, kq = (k >> 3) & 3, j = k & 7;
    size_t dsti = ((((size_t)step * (OUT >> 6) + ob) * 4 + n) * 64 + (kq * 16 + fr)) * 8 + j;
    dst[dsti] = f2bf(src[(size_t)o * stride + off + k]);
}

// all 9 weight packs in one launch (segment dispatch by global index)
__global__ void k_pack_all(const float* __restrict__ msg_w1, const float* __restrict__ Mtd,
                           const float* __restrict__ msg_w2,
                           const float* __restrict__ gru_wih, const float* __restrict__ gru_whh,
                           const float* __restrict__ gat1_w, const float* __restrict__ gat2_w,
                           unsigned short* __restrict__ w1ap, unsigned short* __restrict__ w1bp,
                           unsigned short* __restrict__ w1cp, unsigned short* __restrict__ wtdp,
                           unsigned short* __restrict__ w2p,
                           unsigned short* __restrict__ wihp, unsigned short* __restrict__ whhp,
                           unsigned short* __restrict__ g1p, unsigned short* __restrict__ g2p) {
    int i = blockIdx.x * 256 + threadIdx.x;
    if (i < 65536) { pack_one(msg_w1, w1ap, 256, 256, 576, 0, i); return; }
    i -= 65536;
    if (i < 65536) { pack_one(msg_w1, w1bp, 256, 256, 576, 256, i); return; }
    i -= 65536;
    if (i < 8192)  { pack_one(msg_w1, w1cp, 256, 32, 576, 512, i); return; }
    i -= 8192;
    if (i < 8192)  { pack_one(Mtd, wtdp, 256, 32, 32, 0, i); return; }
    i -= 8192;
    if (i < 65536) { pack_one(msg_w2, w2p, 256, 256, 256, 0, i); return; }
    i -= 65536;
    if (i < 196608) { pack_one(gru_wih, wihp, 768, 256, 256, 0, i); return; }
    i -= 196608;
    if (i < 196608) { pack_one(gru_whh, whhp, 768, 256, 256, 0, i); return; }
    i -= 196608;
    if (i < 65536) { pack_one(gat1_w, g1p, 256, 256, 256, 0, i); return; }
    i -= 65536;
    if (i < 65536) { pack_one(gat2_w, g2p, 256, 256, 256, 0, i); return; }
}

// Mtd[o][i] = sum_c W1d[o][c] * tw2[c][i] ; b1eff[o] = b1[o] + sum_c W1d[o][c]*tb2[c]
__global__ void k_fold_te(const float* __restrict__ msg_w1, const float* __restrict__ tw2,
                          const float* __restrict__ tb2, const float* __restrict__ b1,
                          float* __restrict__ Mtd, float* __restrict__ b1eff) {
    int i = blockIdx.x * 256 + threadIdx.x;
    if (i < 256 * 32) {
        int o = i >> 5, col = i & 31;
        float s = 0.f;
        const float* w1d = msg_w1 + (size_t)o * 576 + 544;
#pragma unroll
        for (int c = 0; c < 32; ++c) s += w1d[c] * tw2[c * 32 + col];
        Mtd[i] = s;
        if (col == 0) {
            float sb = b1[o];
#pragma unroll
            for (int c = 0; c < 32; ++c) sb += w1d[c] * tb2[c];
            b1eff[o] = sb;
        }
    }
}

__global__ void k_timemax(const float* __restrict__ ts, int n, int* out) {
    float m = -INFINITY;
    int stride = gridDim.x * blockDim.x;
    for (int i = blockIdx.x * blockDim.x + threadIdx.x; i < n; i += stride)
        m = fmaxf(m, ts[i]);
    atomicMax(out, enc_f(m));
}

__global__ void k_counts(const int* __restrict__ ei, float* __restrict__ counts) {
    int stride = gridDim.x * blockDim.x;
    for (int i = blockIdx.x * blockDim.x + threadIdx.x; i < NE; i += stride)
        atomicAdd(&counts[ei[NE + i]], 1.f);
}

// ---------- CSR build ----------
__global__ void k_scan1(const float* __restrict__ counts, int* __restrict__ rowptr,
                        int* __restrict__ bsum) {
    __shared__ int sh[256];
    int t = threadIdx.x;
    int i = blockIdx.x * 256 + t;
    int v = (i < NN) ? ((int)counts[i] + 1) : 0;
    sh[t] = v;
    __syncthreads();
    for (int off = 1; off < 256; off <<= 1) {
        int x = (t >= off) ? sh[t - off] : 0;
        __syncthreads();
        sh[t] += x;
        __syncthreads();
    }
    if (i < NN) rowptr[i + 1] = sh[t];
    if (t == 255) bsum[blockIdx.x] = sh[255];
}

__global__ void k_scan2(int* __restrict__ bsum, int nb) {
    __shared__ int sh[512];
    int t = threadIdx.x;
    sh[t] = (t < nb) ? bsum[t] : 0;
    __syncthreads();
    for (int off = 1; off < 512; off <<= 1) {
        int x = (t >= off) ? sh[t - off] : 0;
        __syncthreads();
        sh[t] += x;
        __syncthreads();
    }
    if (t < nb) bsum[t] = sh[t];
}

// finalize rowptr and seed both fill cursors (node CSR + edge-only list)
__global__ void k_scan3(int* __restrict__ rowptr, const int* __restrict__ bsum,
                        int* __restrict__ fillp, int* __restrict__ fillE) {
    int i = blockIdx.x * 256 + threadIdx.x;
    if (i == 0) {
        rowptr[0] = 0;
        fillp[0] = 0;
        fillE[0] = 0;
    }
    if (i < NN) {
        int b = i >> 8;
        int off = b > 0 ? bsum[b - 1] : 0;
        int v = rowptr[i + 1] + off;
        rowptr[i + 1] = v;
        if (i + 1 < NN) {
            fillp[i + 1] = v;
            fillE[i + 1] = v - (i + 1);
        }
    }
}

__global__ void k_csr_fill(const int* __restrict__ ei, int* __restrict__ fill,
                           int* __restrict__ colidx) {
    int i = blockIdx.x * 256 + threadIdx.x;
    if (i < NE) {
        int d = ei[NE + i];
        int pos = atomicAdd(&fill[d], 1);
        colidx[pos] = ei[i];
    } else if (i < NE + NN) {
        int n = i - NE;
        int pos = atomicAdd(&fill[n], 1);
        colidx[pos] = n;
    }
}

__global__ void k_ecsr_fill(const int* __restrict__ ei, int* __restrict__ fillE,
                            int* __restrict__ esrc, int* __restrict__ edst) {
    int i = blockIdx.x * 256 + threadIdx.x;
    if (i < NE) {
        int d = ei[NE + i];
        int pos = atomicAdd(&fillE[d], 1);
        esrc[pos] = ei[i];
        edst[pos] = d;
    }
}

// ---------- per-node precompute: P13/P2 + bf16 copy of mem (membf) ----------
__global__ __launch_bounds__(512, 4) void k_pre1(
    const float* __restrict__ mem, const float* __restrict__ x,
    const unsigned short* __restrict__ w1ap, const unsigned short* __restrict__ w1bp,
    const unsigned short* __restrict__ w1cp,
    unsigned short* __restrict__ P13, unsigned short* __restrict__ P2,
    unsigned short* __restrict__ membf) {
    __shared__ unsigned short Af[2 * 8 * GPLANE];
    __shared__ unsigned short Axf[2 * 512];
    const int t = threadIdx.x;
    const int lane = t & 63, w = t >> 6;
    const int row0 = blockIdx.x * 32;
    const int frow = lane & 15, hi = lane >> 4;
    const int half = w >> 2, cq = w & 3;

    {
        int sr = t >> 4, sq = t & 15;
        int row = row0 + sr;
        const float* pm = mem + (size_t)row * 256 + sq * 16;
        int smq = sr >> 4, sfr = sr & 15;
#pragma unroll
        for (int j2 = 0; j2 < 2; ++j2) {
            int k8 = sq * 16 + j2 * 8;
            int st = k8 >> 5, kq = (k8 >> 3) & 3;
            float4 m0 = *(const float4*)(pm + j2 * 8);
            float4 m1 = *(const float4*)(pm + j2 * 8 + 4);
            ushort8v um;
            um[0] = f2bf(m0.x); um[1] = f2bf(m0.y); um[2] = f2bf(m0.z); um[3] = f2bf(m0.w);
            um[4] = f2bf(m1.x); um[5] = f2bf(m1.y); um[6] = f2bf(m1.z); um[7] = f2bf(m1.w);
            *(ushort8v*)&Af[((smq * 8) + st) * GPLANE + (kq * 16 + sfr) * 8] = um;
            *(ushort8v*)(membf + (size_t)row * 256 + k8) = um;
        }
    }
    if (t < 128) {
        int sr = t >> 2, sq = t & 3;
        int row = row0 + sr;
        const float* px = x + (size_t)row * 32 + sq * 8;
        float4 v0 = *(const float4*)px, v1 = *(const float4*)(px + 4);
        ushort8v u;
        u[0] = f2bf(v0.x); u[1] = f2bf(v0.y); u[2] = f2bf(v0.z); u[3] = f2bf(v0.w);
        u[4] = f2bf(v1.x); u[5] = f2bf(v1.y); u[6] = f2bf(v1.z); u[7] = f2bf(v1.w);
        *(ushort8v*)&Axf[(sr >> 4) * 512 + (sq * 16 + (sr & 15)) * 8] = u;
    }
    __syncthreads();

    f32x4 acc[2][4];
#pragma unroll
    for (int mf = 0; mf < 2; ++mf)
#pragma unroll
        for (int c = 0; c < 4; ++c) acc[mf][c] = (f32x4){0, 0, 0, 0};

    const unsigned short* wp = half ? w1bp : w1ap;
    for (int step = 0; step < 8; ++step) {
        bf16x8 aA[2];
#pragma unroll
        for (int mf = 0; mf < 2; ++mf)
            aA[mf] = *(const bf16x8*)&Af[((mf * 8) + step) * GPLANE + lane * 8];
#pragma unroll
        for (int ctl = 0; ctl < 4; ++ctl) {
            bf16x8 b = *(const bf16x8*)(wp + (((size_t)step * 4 + cq) * 4 + ctl) * 512 + lane * 8);
#pragma unroll
            for (int mf = 0; mf < 2; ++mf)
                acc[mf][ctl] = __builtin_amdgcn_mfma_f32_16x16x32_bf16(aA[mf], b, acc[mf][ctl], 0, 0, 0);
        }
    }
    if (half == 0) {
        bf16x8 aX[2];
#pragma unroll
        for (int mf = 0; mf < 2; ++mf)
            aX[mf] = *(const bf16x8*)&Axf[mf * 512 + lane * 8];
#pragma unroll
        for (int ctl = 0; ctl < 4; ++ctl) {
            bf16x8 b = *(const bf16x8*)(w1cp + (((size_t)0 * 4 + cq) * 4 + ctl) * 512 + lane * 8);
#pragma unroll
            for (int mf = 0; mf < 2; ++mf)
                acc[mf][ctl] = __builtin_amdgcn_mfma_f32_16x16x32_bf16(aX[mf], b, acc[mf][ctl], 0, 0, 0);
        }
    }
    unsigned short* P = half ? P2 : P13;
#pragma unroll
    for (int mf = 0; mf < 2; ++mf)
#pragma unroll
        for (int ctl = 0; ctl < 4; ++ctl) {
            int col = cq * 64 + ctl * 16 + frow;
#pragma unroll
            for (int r = 0; r < 4; ++r) {
                int row = row0 + mf * 16 + hi * 4 + r;
                P[(size_t)row * 256 + col] = f2bf(acc[mf][ctl][r]);
            }
        }
}

// ---------- edge message kernel, 512 thr (8 waves x 64x32 out) ----------
__global__ __launch_bounds__(512, 4) void k_msg_mfma(
    const int* __restrict__ ct, const float* __restrict__ lut,
    const int* __restrict__ esrc, const int* __restrict__ edst,
    const unsigned short* __restrict__ P13, const unsigned short* __restrict__ P2,
    const unsigned short* __restrict__ wtdp, const float* __restrict__ b1eff,
    const unsigned short* __restrict__ w2p, const float* __restrict__ b2,
    const float* __restrict__ tw1, const float* __restrict__ tb1,
    float* __restrict__ agg) {
    __shared__ unsigned short As[64][40];
    __shared__ unsigned short Hs[64][264];
    __shared__ int Da[64];

    const int t = threadIdx.x;
    const int lane = t & 63, wave = t >> 6;
    const int row0 = blockIdx.x * 64;
    const int frow = lane & 15;
    const int fk = (lane >> 4) * 8;
    const int hi = lane >> 4;
    const int wb = wave >> 1;
    const int wn = (wave & 1) * 2;

    if (t < 64) {
        int e = row0 + t;
        Da[t] = (e < NE) ? edst[e] : -1;
    }

    const int srow = t >> 3;
    const int sj = t & 7;
    const int eIdx = row0 + srow;
    const bool ev = eIdx < NE;
    const int s_e = ev ? esrc[eIdx] : 0;
    const int d_e = ev ? edst[eIdx] : 0;

    {
        float ctv = dec_f(*ct);
        float dt = ev ? (ctv - fmaxf(lut[s_e], lut[d_e])) : 0.f;
        ushort4 u;
        int c0 = sj * 4;
        u.x = f2bf(fmaxf(dt * tw1[c0 + 0] + tb1[c0 + 0], 0.f));
        u.y = f2bf(fmaxf(dt * tw1[c0 + 1] + tb1[c0 + 1], 0.f));
        u.z = f2bf(fmaxf(dt * tw1[c0 + 2] + tb1[c0 + 2], 0.f));
        u.w = f2bf(fmaxf(dt * tw1[c0 + 3] + tb1[c0 + 3], 0.f));
        *(ushort4*)&As[srow][c0] = u;
    }
#pragma unroll
    for (int q = 0; q < 4; ++q) {
        int c = sj * 8 + q * 64;
        ushort4 a0 = *(const ushort4*)(P13 + (size_t)s_e * 256 + c);
        ushort4 a1 = *(const ushort4*)(P13 + (size_t)s_e * 256 + c + 4);
        ushort4 b0 = *(const ushort4*)(P2 + (size_t)d_e * 256 + c);
        ushort4 b1v = *(const ushort4*)(P2 + (size_t)d_e * 256 + c + 4);
        ushort8v u;
        u[0] = f2bf(bf2f(a0.x) + bf2f(b0.x)); u[1] = f2bf(bf2f(a0.y) + bf2f(b0.y));
        u[2] = f2bf(bf2f(a0.z) + bf2f(b0.z)); u[3] = f2bf(bf2f(a0.w) + bf2f(b0.w));
        u[4] = f2bf(bf2f(a1.x) + bf2f(b1v.x)); u[5] = f2bf(bf2f(a1.y) + bf2f(b1v.y));
        u[6] = f2bf(bf2f(a1.z) + bf2f(b1v.z)); u[7] = f2bf(bf2f(a1.w) + bf2f(b1v.w));
        *(ushort8v*)&Hs[srow][c] = u;
    }
    __syncthreads();

    f32x4 acc[4][2];
#pragma unroll
    for (int m = 0; m < 4; m++)
#pragma unroll
        for (int n = 0; n < 2; n++) acc[m][n] = (f32x4){0.f, 0.f, 0.f, 0.f};

    {
        bf16x8 a[4];
#pragma unroll
        for (int m = 0; m < 4; m++)
            a[m] = *(const bf16x8*)&As[m * 16 + frow][fk];
#pragma unroll
        for (int n = 0; n < 2; n++) {
            bf16x8 b = *(const bf16x8*)(wtdp + (((size_t)0 * 4 + wb) * 4 + (wn + n)) * 512 + lane * 8);
#pragma unroll
            for (int m = 0; m < 4; m++)
                acc[m][n] = __builtin_amdgcn_mfma_f32_16x16x32_bf16(a[m], b, acc[m][n], 0, 0, 0);
        }
    }
#pragma unroll
    for (int n = 0; n < 2; n++) {
        int c = wave * 32 + n * 16 + frow;
        float bb = b1eff[c];
#pragma unroll
        for (int m = 0; m < 4; m++) {
#pragma unroll
            for (int r = 0; r < 4; r++) {
                int rr = m * 16 + hi * 4 + r;
                float v = acc[m][n][r] + bf2f(Hs[rr][c]) + bb;
                Hs[rr][c] = f2bf(fmaxf(v, 0.f));
            }
            acc[m][n] = (f32x4){0.f, 0.f, 0.f, 0.f};
        }
    }
    __syncthreads();

    bf16x8 bnext[2];
#pragma unroll
    for (int n = 0; n < 2; n++)
        bnext[n] = *(const bf16x8*)(w2p + (((size_t)0 * 4 + wb) * 4 + (wn + n)) * 512 + lane * 8);
    for (int step = 0; step < 8; ++step) {
        const int k0 = step * 32;
        bf16x8 bcur[2];
#pragma unroll
        for (int n = 0; n < 2; n++) bcur[n] = bnext[n];
        if (step < 7) {
#pragma unroll
            for (int n = 0; n < 2; n++)
                bnext[n] = *(const bf16x8*)(w2p + (((size_t)(step + 1) * 4 + wb) * 4 + (wn + n)) * 512 + lane * 8);
        }
        bf16x8 a[4];
#pragma unroll
        for (int m = 0; m < 4; m++)
            a[m] = *(const bf16x8*)&Hs[m * 16 + frow][k0 + fk];
#pragma unroll
        for (int m = 0; m < 4; m++)
#pragma unroll
            for (int n = 0; n < 2; n++)
                acc[m][n] = __builtin_amdgcn_mfma_f32_16x16x32_bf16(a[m], bcur[n], acc[m][n], 0, 0, 0);
    }

    __syncthreads();
    {
        float bb2[2];
#pragma unroll
        for (int n = 0; n < 2; n++) bb2[n] = b2[wave * 32 + n * 16 + frow];
#pragma unroll
        for (int m = 0; m < 4; m++) {
            int rbase = m * 16 + hi * 4;
#pragma unroll
            for (int r = 0; r < 4; r++) {
#pragma unroll
                for (int n = 0; n < 2; n++)
                    Hs[rbase + r][wave * 32 + n * 16 + frow] = f2bf(acc[m][n][r] + bb2[n]);
            }
        }
        __syncthreads();

        int nrows = min(64, NE - row0);
        int col = t & 255;
        int rs = (t >> 8) * 32;
        int re = min(nrows, rs + 32);
        if (rs < re) {
            float run = 0.f;
            int cur = Da[rs];
            for (int i = rs; i < re; ++i) {
                int d = Da[i];
                if (d != cur) {
                    atomicAdd(agg + (size_t)cur * 256 + col, run);
                    run = 0.f;
                    cur = d;
                }
                run += bf2f(Hs[i][col]);
            }
            atomicAdd(agg + (size_t)cur * 256 + col, run);
        }
    }
}

// ---------- GRU, bf16 MFMA v9: v8 + division-free fast gates ----------
__global__ __launch_bounds__(1024, 8) void k_gru_mfma(
    const float* __restrict__ agg, const unsigned short* __restrict__ membf,
    const float* __restrict__ counts,
    const unsigned short* __restrict__ pwih, const unsigned short* __restrict__ pwhh,
    const float* __restrict__ bih, const float* __restrict__ bhh,
    unsigned short* __restrict__ memout) {
    __shared__ unsigned short Af[2 * 2 * 8 * GPLANE];
    const int t = threadIdx.x;
    const int lane = t & 63, w = t >> 6;       // wave 0..15
    const int row0 = blockIdx.x * 32;
    const int frow = lane & 15, hi = lane >> 4;
    const int cqp = w >> 2;                     // 64-col block (0..3)
    const int ctl = w & 3;                      // 16-col frag within it

    // stage A once: 1024 threads x 8 floats = 32 rows x 256 cols
    {
        int sr = t >> 5, sq = t & 31;           // row 0..31, 8-float chunk 0..31
        int row = row0 + sr;
        float inv = 1.f / fmaxf(counts[row], 1.f);
        int k8 = sq * 8;
        int st = k8 >> 5, kq = (k8 >> 3) & 3;
        const float* pa = agg + (size_t)row * 256 + k8;
        const unsigned short* pm = membf + (size_t)row * 256 + k8;
        float4 a0 = *(const float4*)pa;
        float4 a1 = *(const float4*)(pa + 4);
        ushort8v um = *(const ushort8v*)pm;
        ushort8v ua;
        ua[0] = f2bf(a0.x * inv); ua[1] = f2bf(a0.y * inv); ua[2] = f2bf(a0.z * inv); ua[3] = f2bf(a0.w * inv);
        ua[4] = f2bf(a1.x * inv); ua[5] = f2bf(a1.y * inv); ua[6] = f2bf(a1.z * inv); ua[7] = f2bf(a1.w * inv);
        int smq = sr >> 4, sfr = sr & 15;
        int pos = kq * 16 + sfr;
        *(ushort8v*)&Af[(((0 * 2 + smq) * 8) + st) * GPLANE + pos * 8] = ua;
        *(ushort8v*)&Af[(((1 * 2 + smq) * 8) + st) * GPLANE + pos * 8] = um;
    }
    __syncthreads();

    f32x4 rpre[2], zpre[2], inn[2], hn[2];
#pragma unroll
    for (int mf = 0; mf < 2; ++mf) {
        rpre[mf] = (f32x4){0, 0, 0, 0};
        zpre[mf] = (f32x4){0, 0, 0, 0};
        inn[mf]  = (f32x4){0, 0, 0, 0};
        hn[mf]   = (f32x4){0, 0, 0, 0};
    }

    for (int step = 0; step < 8; ++step) {
        bf16x8 aA[2], aM[2];
#pragma unroll
        for (int mf = 0; mf < 2; ++mf) {
            aA[mf] = *(const bf16x8*)&Af[(((0 * 2 + mf) * 8) + step) * GPLANE + lane * 8];
            aM[mf] = *(const bf16x8*)&Af[(((1 * 2 + mf) * 8) + step) * GPLANE + lane * 8];
        }
        size_t o_r = (((size_t)step * 12 + 0 * 4 + cqp) * 4 + ctl) * 512 + lane * 8;
        size_t o_z = (((size_t)step * 12 + 1 * 4 + cqp) * 4 + ctl) * 512 + lane * 8;
        size_t o_n = (((size_t)step * 12 + 2 * 4 + cqp) * 4 + ctl) * 512 + lane * 8;
        bf16x8 bIr = *(const bf16x8*)(pwih + o_r);
        bf16x8 bHr = *(const bf16x8*)(pwhh + o_r);
        bf16x8 bIz = *(const bf16x8*)(pwih + o_z);
        bf16x8 bHz = *(const bf16x8*)(pwhh + o_z);
        bf16x8 bIn = *(const bf16x8*)(pwih + o_n);
        bf16x8 bHn = *(const bf16x8*)(pwhh + o_n);
#pragma unroll
        for (int mf = 0; mf < 2; ++mf) {
            rpre[mf] = __builtin_amdgcn_mfma_f32_16x16x32_bf16(aA[mf], bIr, rpre[mf], 0, 0, 0);
            rpre[mf] = __builtin_amdgcn_mfma_f32_16x16x32_bf16(aM[mf], bHr, rpre[mf], 0, 0, 0);
            zpre[mf] = __builtin_amdgcn_mfma_f32_16x16x32_bf16(aA[mf], bIz, zpre[mf], 0, 0, 0);
            zpre[mf] = __builtin_amdgcn_mfma_f32_16x16x32_bf16(aM[mf], bHz, zpre[mf], 0, 0, 0);
            inn[mf]  = __builtin_amdgcn_mfma_f32_16x16x32_bf16(aA[mf], bIn, inn[mf], 0, 0, 0);
            hn[mf]   = __builtin_amdgcn_mfma_f32_16x16x32_bf16(aM[mf], bHn, hn[mf], 0, 0, 0);
        }
    }

    const int col = cqp * 64 + ctl * 16 + frow;
    const float br = bih[col] + bhh[col];
    const float bz = bih[256 + col] + bhh[256 + col];
    const float bin = bih[512 + col];
    const float bhn = bhh[512 + col];
#pragma unroll
    for (int mf = 0; mf < 2; ++mf)
#pragma unroll
        for (int r = 0; r < 4; ++r) {
            int row = row0 + mf * 16 + hi * 4 + r;
            float cnt = counts[row];
            // division-free fast gates: sigmoid = rcp(1+exp(-x)),
            // tanh(y) = (1-t)*rcp(1+t), t = exp(-2*max(y,-44)) <= e^88 (finite)
            float er = __expf(-(rpre[mf][r] + br));
            float rg = __builtin_amdgcn_rcpf(1.f + er);
            float ez = __expf(-(zpre[mf][r] + bz));
            float zg = __builtin_amdgcn_rcpf(1.f + ez);
            float y = inn[mf][r] + bin + rg * (hn[mf][r] + bhn);
            float ty = __expf(-2.f * fmaxf(y, -44.f));
            float ng = (1.f - ty) * __builtin_amdgcn_rcpf(1.f + ty);
            int pos = ((col >> 3) & 3) * 16 + (hi * 4 + r);
            float hp = bf2f(Af[(((1 * 2 + mf) * 8) + (col >> 5)) * GPLANE + pos * 8 + (col & 7)]);
            memout[(size_t)row * 256 + col] = f2bf((cnt > 0.f) ? ((1.f - zg) * ng + zg * hp) : hp);
        }
}

// ---------- GAT xh GEMM + attention-logit fusion; LDS-staged A tile ----------
__global__ __launch_bounds__(256, 4) void k_xh_mfma(
    const unsigned short* __restrict__ A, const unsigned short* __restrict__ wp,
    const float* __restrict__ asrc, const float* __restrict__ adst,
    unsigned short* __restrict__ xh, float* __restrict__ als, float* __restrict__ ald) {
    __shared__ unsigned short Af[4 * 8 * GPLANE];
    const int t = threadIdx.x;
    const int lane = t & 63, w = t >> 6;
    const int row0 = blockIdx.x * 64;
    const int frow = lane & 15, hi = lane >> 4;

    // stage 64 rows x 256 cols (bf16, pure relayout) into fragment-major LDS.
    // thread t: row sr = t>>2, 64-col chunk sq = t&3 -> 128 B coalesced per lane.
    {
        int sr = t >> 2, sq = t & 3;
        int row = min(row0 + sr, NN - 1);
        const unsigned short* pa = A + (size_t)row * 256 + sq * 64;
        int rg = sr >> 4, fr = sr & 15;
#pragma unroll
        for (int j = 0; j < 8; ++j) {
            int k8 = sq * 64 + j * 8;
            int st = k8 >> 5, kq = (k8 >> 3) & 3;
            *(ushort8v*)&Af[((rg * 8) + st) * GPLANE + (kq * 16 + fr) * 8] =
                *(const ushort8v*)(pa + j * 8);
        }
    }
    __syncthreads();

    f32x4 acc[4][4];
#pragma unroll
    for (int m = 0; m < 4; m++)
#pragma unroll
        for (int c = 0; c < 4; c++) acc[m][c] = (f32x4){0, 0, 0, 0};

    for (int step = 0; step < 8; ++step) {
        bf16x8 a[4];
#pragma unroll
        for (int m = 0; m < 4; ++m)
            a[m] = *(const bf16x8*)&Af[((m * 8) + step) * GPLANE + lane * 8];
#pragma unroll
        for (int ctl = 0; ctl < 4; ++ctl) {
            bf16x8 b = *(const bf16x8*)(wp + (((size_t)step * 4 + w) * 4 + ctl) * 512 + lane * 8);
#pragma unroll
            for (int m = 0; m < 4; ++m)
                acc[m][ctl] = __builtin_amdgcn_mfma_f32_16x16x32_bf16(a[m], b, acc[m][ctl], 0, 0, 0);
        }
    }

    float asv[4], adv[4];
#pragma unroll
    for (int ctl = 0; ctl < 4; ++ctl) {
        asv[ctl] = asrc[w * 64 + ctl * 16 + frow];
        adv[ctl] = adst[w * 64 + ctl * 16 + frow];
    }
#pragma unroll
    for (int m = 0; m < 4; ++m) {
        float ps[4] = {0, 0, 0, 0}, pd[4] = {0, 0, 0, 0};
#pragma unroll
        for (int ctl = 0; ctl < 4; ++ctl) {
            int col = w * 64 + ctl * 16 + frow;
#pragma unroll
            for (int r = 0; r < 4; ++r) {
                float v = acc[m][ctl][r];
                ps[r] += v * asv[ctl];
                pd[r] += v * adv[ctl];
                int row = row0 + m * 16 + hi * 4 + r;
                if (row < NN) xh[(size_t)row * 256 + col] = f2bf(v);
            }
        }
#pragma unroll
        for (int off = 1; off < 16; off <<= 1) {
#pragma unroll
            for (int r = 0; r < 4; ++r) {
                ps[r] += __shfl_xor(ps[r], off, 64);
                pd[r] += __shfl_xor(pd[r], off, 64);
            }
        }
        if (frow == 0) {
#pragma unroll
            for (int r = 0; r < 4; ++r) {
                int row = row0 + m * 16 + hi * 4 + r;
                if (row < NN) { als[row * 4 + w] = ps[r]; ald[row * 4 + w] = pd[r]; }
            }
        }
    }
}

// ---------- fused GAT edge-softmax + aggregate, CSR, single-pass ----------
__global__ __launch_bounds__(256) void k_gat_csr(
    const int* __restrict__ rowptr, const int* __restrict__ colidx,
    const float* __restrict__ als, const float* __restrict__ ald,
    const unsigned short* __restrict__ xh, const float* __restrict__ bias,
    unsigned short* __restrict__ outb) {
    int d = blockIdx.x * 4 + (threadIdx.x >> 6);
    if (d >= NN) return;
    int lane = threadIdx.x & 63;
    int h = lane >> 4;
    int beg = rowptr[d], end = rowptr[d + 1];
    float aldv = ald[d * 4 + h];

    float den = 0.f;
    float a0 = 0.f, a1 = 0.f, a2 = 0.f, a3 = 0.f;
    for (int p = beg; p < end; ++p) {
        int s = colidx[p];
        float e = als[s * 4 + h] + aldv;
        e = e > 0.f ? e : 0.2f * e;
        float pw = __expf(e);
        den += pw;
        ushort4 uv = *(const ushort4*)(xh + (size_t)s * 256 + lane * 4);
        a0 += pw * bf2f(uv.x);
        a1 += pw * bf2f(uv.y);
        a2 += pw * bf2f(uv.z);
        a3 += pw * bf2f(uv.w);
    }
    float inv = 1.f / den;
    int c = lane * 4;
    float4 bv = *(const float4*)(bias + c);
    float ox = a0 * inv + bv.x; ox = ox > 0.f ? ox : expm1f(ox);
    float oy = a1 * inv + bv.y; oy = oy > 0.f ? oy : expm1f(oy);
    float oz = a2 * inv + bv.z; oz = oz > 0.f ? oz : expm1f(oz);
    float ow = a3 * inv + bv.w; ow = ow > 0.f ? ow : expm1f(ow);
    ushort4 o;
    o.x = f2bf(ox); o.y = f2bf(oy); o.z = f2bf(oz); o.w = f2bf(ow);
    *(ushort4*)(outb + (size_t)d * 256 + c) = o;
}

__global__ __launch_bounds__(256) void k_pool(const unsigned short* __restrict__ h,
                                              const int* __restrict__ batch, float* __restrict__ gsum) {
    int t = threadIdx.x;
    const int per = (NN + gridDim.x - 1) / gridDim.x;
    int n0 = blockIdx.x * per, n1 = min(NN, n0 + per);
    float s = 0.f, cnt = 0.f;
    for (int n = n0; n < n1; n++) {
        if (batch[n] == 0) {
            s += bf2f(h[(size_t)n * 256 + t]);
            cnt += 1.f;
        }
    }
    atomicAdd(&gsum[t], s);
    if (t == 0) atomicAdd(&gsum[256], cnt);
}

__global__ void k_cls(const float* __restrict__ gsum, const float* __restrict__ w1,
                      const float* __restrict__ b1, const float* __restrict__ w2,
                      const float* __restrict__ b2, float* __restrict__ out) {
    __shared__ float g[256];
    __shared__ float hid[128];
    int t = threadIdx.x;
    float gc = gsum[256];
    g[t] = gsum[t] / gc;
    __syncthreads();
    if (t < 128) {
        float s = b1[t];
        for (int k = 0; k < 256; k++) s += g[k] * w1[t * 256 + k];
        hid[t] = fmaxf(s, 0.f);
    }
    __syncthreads();
    if (t < 2) {
        float s = b2[t];
        for (int k = 0; k < 128; k++) s += hid[k] * w2[t * 128 + k];
        out[t] = s;
    }
}

// ---------- launch ----------
extern "C" void kernel_launch(void* const* d_in, const int* in_sizes, int n_in,
                              void* d_out, int out_size, void* d_ws, size_t ws_size,
                              hipStream_t stream) {
    const float* xv      = (const float*)d_in[0];
    const float* tsv     = (const float*)d_in[1];
    const float* nodemem = (const float*)d_in[2];
    const float* lut     = (const float*)d_in[3];
    const float* msg_w1  = (const float*)d_in[4];
    const float* msg_b1  = (const float*)d_in[5];
    const float* msg_w2  = (const float*)d_in[6];
    const float* msg_b2  = (const float*)d_in[7];
    const float* time_w1 = (const float*)d_in[8];
    const float* time_b1 = (const float*)d_in[9];
    const float* time_w2 = (const float*)d_in[10];
    const float* time_b2 = (const float*)d_in[11];
    const float* gru_wih = (const float*)d_in[12];
    const float* gru_whh = (const float*)d_in[13];
    const float* gru_bih = (const float*)d_in[14];
    const float* gru_bhh = (const float*)d_in[15];
    const float* gat1_w    = (const float*)d_in[16];
    const float* gat1_asrc = (const float*)d_in[17];
    const float* gat1_adst = (const float*)d_in[18];
    const float* gat1_b    = (const float*)d_in[19];
    const float* gat2_w    = (const float*)d_in[20];
    const float* gat2_asrc = (const float*)d_in[21];
    const float* gat2_adst = (const float*)d_in[22];
    const float* gat2_b    = (const float*)d_in[23];
    const float* cls_w1 = (const float*)d_in[24];
    const float* cls_b1 = (const float*)d_in[25];
    const float* cls_w2 = (const float*)d_in[26];
    const float* cls_b2 = (const float*)d_in[27];
    const int* ei    = (const int*)d_in[28];
    const int* batch = (const int*)d_in[29];
    float* out = (float*)d_out;

    char* wsb = (char*)d_ws;
    size_t off = 0;
    auto carve = [&](size_t bytes) {
        char* p = wsb + off;
        off += (bytes + 255) & ~(size_t)255;
        return p;
    };
    int*   curtime = (int*)carve(4);
    unsigned short* w1ap = (unsigned short*)carve((size_t)256 * 256 * 2);
    unsigned short* w1bp = (unsigned short*)carve((size_t)256 * 256 * 2);
    unsigned short* w1cp = (unsigned short*)carve((size_t)256 * 32 * 2);
    unsigned short* wtdp = (unsigned short*)carve((size_t)256 * 32 * 2);
    unsigned short* w2p  = (unsigned short*)carve((size_t)256 * 256 * 2);
    unsigned short* wihp = (unsigned short*)carve((size_t)768 * 256 * 2);
    unsigned short* whhp = (unsigned short*)carve((size_t)768 * 256 * 2);
    unsigned short* g1p  = (unsigned short*)carve((size_t)256 * 256 * 2);
    unsigned short* g2p  = (unsigned short*)carve((size_t)256 * 256 * 2);
    float* Mtd   = (float*)carve((size_t)256 * 32 * 4);
    float* b1eff = (float*)carve(256 * 4);
    unsigned short* P13  = (unsigned short*)carve((size_t)NN * 256 * 2);
    unsigned short* P2   = (unsigned short*)carve((size_t)NN * 256 * 2);
    unsigned short* membf = (unsigned short*)carve((size_t)NN * 256 * 2);
    float* als    = (float*)carve((size_t)NN * 4 * 4);
    float* ald    = (float*)carve((size_t)NN * 4 * 4);
    float* counts = (float*)carve((size_t)NN * 4);
    float* gsum   = (float*)carve(257 * 4);
    int*   rowptr = (int*)carve((size_t)(NN + 1) * 4);
    int*   colidx = (int*)carve((size_t)(NE + NN) * 4);
    int*   fillp  = (int*)carve((size_t)NN * 4);
    int*   bsum   = (int*)carve(512 * 4);
    int*   esrc   = (int*)carve((size_t)NE * 4);
    int*   edst   = (int*)carve((size_t)NE * 4);
    int*   fillE  = (int*)carve((size_t)NN * 4);
    float* R1     = (float*)carve((size_t)NN * 256 * 4);  // agg -> xh1(bf16) -> xh2(bf16)
    float* R2     = (float*)carve((size_t)NN * 256 * 4);  // memo/outb1/outb2 (bf16)

    if (ws_size < off) {
        k_dbg<<<1, 1, 0, stream>>>(out, (float)(ws_size >> 20));
        return;
    }

    float* agg   = R1;
    unsigned short* memo  = (unsigned short*)R2;
    unsigned short* xh1   = (unsigned short*)R1;
    unsigned short* xh2   = (unsigned short*)R1;
    unsigned short* outb1 = (unsigned short*)R2;
    unsigned short* outb2 = (unsigned short*)R2;

    // ---- init ----
    hipMemsetAsync(agg, 0, (size_t)NN * 256 * 4, stream);
    hipMemsetAsync(counts, 0, (size_t)NN * 4, stream);
    hipMemsetAsync(gsum, 0, 257 * 4, stream);
    k_fill_i32<<<1, 256, 0, stream>>>(curtime, (int)0x80000000, 1);

    // ---- weight prep: fold te weights, then ALL packs in one launch ----
    k_fold_te<<<32, 256, 0, stream>>>(msg_w1, time_w2, time_b2, msg_b1, Mtd, b1eff);
    k_pack_all<<<2880, 256, 0, stream>>>(msg_w1, Mtd, msg_w2, gru_wih, gru_whh,
                                         gat1_w, gat2_w,
                                         w1ap, w1bp, w1cp, wtdp, w2p,
                                         wihp, whhp, g1p, g2p);

    // ---- counts + CSR build ----
    k_counts<<<1024, 256, 0, stream>>>(ei, counts);
    k_scan1<<<391, 256, 0, stream>>>(counts, rowptr, bsum);
    k_scan2<<<1, 512, 0, stream>>>(bsum, 391);
    k_scan3<<<391, 256, 0, stream>>>(rowptr, bsum, fillp, fillE);
    k_csr_fill<<<1563, 256, 0, stream>>>(ei, fillp, colidx);
    k_ecsr_fill<<<1172, 256, 0, stream>>>(ei, fillE, esrc, edst);

    // ---- per-node precompute + messages + memory update ----
    k_timemax<<<512, 256, 0, stream>>>(tsv, NE, curtime);
    k_pre1<<<3125, 512, 0, stream>>>(nodemem, xv, w1ap, w1bp, w1cp, P13, P2, membf);
    k_msg_mfma<<<4688, 512, 0, stream>>>(curtime, lut, esrc, edst, P13, P2,
                                         wtdp, b1eff, w2p, msg_b2,
                                         time_w1, time_b1, agg);
    k_gru_mfma<<<3125, 1024, 0, stream>>>(agg, membf, counts, wihp, whhp,
                                          gru_bih, gru_bhh, memo);

    // ---- GAT layer 1 ----
    k_xh_mfma<<<1563, 256, 0, stream>>>(memo, g1p, gat1_asrc, gat1_adst, xh1, als, ald);
    k_gat_csr<<<25000, 256, 0, stream>>>(rowptr, colidx, als, ald, xh1, gat1_b, outb1);

    // ---- GAT layer 2 ----
    k_xh_mfma<<<1563, 256, 0, stream>>>(outb1, g2p, gat2_asrc, gat2_adst, xh2, als, ald);
    k_gat_csr<<<25000, 256, 0, stream>>>(rowptr, colidx, als, ald, xh2, gat2_b, outb2);

    // ---- pool + classifier ----
    k_pool<<<2048, 256, 0, stream>>>(outb2, batch, gsum);
    k_cls<<<1, 256, 0, stream>>>(gsum, cls_w1, cls_b1, cls_w2, cls_b2, out);
}

// Round 29
// 708.474 us; speedup vs baseline: 1.0724x; 1.0162x over previous
//
#include <hip/hip_runtime.h>

#define NN 100000      // nodes
#define NE 300000      // edges
#define GPLANE 528     // shorts per LDS fragment plane (512 + 16 pad)

typedef float f32x4 __attribute__((ext_vector_type(4)));
typedef __bf16 bf16x8 __attribute__((ext_vector_type(8)));
typedef unsigned short ushort8v __attribute__((ext_vector_type(8)));

// ---------- helpers ----------
__device__ __forceinline__ int enc_f(float f) {
    int i = __float_as_int(f);
    return i >= 0 ? i : (i ^ 0x7fffffff);
}
__device__ __forceinline__ float dec_f(int i) {
    return __int_as_float(i >= 0 ? i : (i ^ 0x7fffffff));
}
__device__ __forceinline__ unsigned short f2bf(float f) {
    unsigned u = __float_as_uint(f);
    u += 0x7fffu + ((u >> 16) & 1u);
    return (unsigned short)(u >> 16);
}
__device__ __forceinline__ float bf2f(unsigned short u) {
    return __uint_as_float((unsigned)u << 16);
}

__global__ void k_dbg(float* out, float v) { out[0] = v; out[1] = v; }

__global__ void k_fill_i32(int* p, int v, int n) {
    int i = blockIdx.x * 256 + threadIdx.x;
    if (i < n) p[i] = v;
}

// pack W[o][off+k] (row stride `stride`) -> fragment-major bf16
__device__ __forceinline__ void pack_one(const float* __restrict__ src,
                                         unsigned short* __restrict__ dst,
                                         int OUT, int K, int stride, int off, int i) {
    int o = i / K, k = i % K;
    int ob = o >> 6, n = (o >> 4) & 3, fr = o & 15;
    int step = k >> 5, kq = (k >> 3) & 3, j = k & 7;
    size_t dsti = ((((size_t)step * (OUT >> 6) + ob) * 4 + n) * 64 + (kq * 16 + fr)) * 8 + j;
    dst[dsti] = f2bf(src[(size_t)o * stride + off + k]);
}

// all 9 weight packs in one launch (segment dispatch by global index)
__global__ void k_pack_all(const float* __restrict__ msg_w1, const float* __restrict__ Mtd,
                           const float* __restrict__ msg_w2,
                           const float* __restrict__ gru_wih, const float* __restrict__ gru_whh,
                           const float* __restrict__ gat1_w, const float* __restrict__ gat2_w,
                           unsigned short* __restrict__ w1ap, unsigned short* __restrict__ w1bp,
                           unsigned short* __restrict__ w1cp, unsigned short* __restrict__ wtdp,
                           unsigned short* __restrict__ w2p,
                           unsigned short* __restrict__ wihp, unsigned short* __restrict__ whhp,
                           unsigned short* __restrict__ g1p, unsigned short* __restrict__ g2p) {
    int i = blockIdx.x * 256 + threadIdx.x;
    if (i < 65536) { pack_one(msg_w1, w1ap, 256, 256, 576, 0, i); return; }
    i -= 65536;
    if (i < 65536) { pack_one(msg_w1, w1bp, 256, 256, 576, 256, i); return; }
    i -= 65536;
    if (i < 8192)  { pack_one(msg_w1, w1cp, 256, 32, 576, 512, i); return; }
    i -= 8192;
    if (i < 8192)  { pack_one(Mtd, wtdp, 256, 32, 32, 0, i); return; }
    i -= 8192;
    if (i < 65536) { pack_one(msg_w2, w2p, 256, 256, 256, 0, i); return; }
    i -= 65536;
    if (i < 196608) { pack_one(gru_wih, wihp, 768, 256, 256, 0, i); return; }
    i -= 196608;
    if (i < 196608) { pack_one(gru_whh, whhp, 768, 256, 256, 0, i); return; }
    i -= 196608;
    if (i < 65536) { pack_one(gat1_w, g1p, 256, 256, 256, 0, i); return; }
    i -= 65536;
    if (i < 65536) { pack_one(gat2_w, g2p, 256, 256, 256, 0, i); return; }
}

// Mtd[o][i] = sum_c W1d[o][c] * tw2[c][i] ; b1eff[o] = b1[o] + sum_c W1d[o][c]*tb2[c]
__global__ void k_fold_te(const float* __restrict__ msg_w1, const float* __restrict__ tw2,
                          const float* __restrict__ tb2, const float* __restrict__ b1,
                          float* __restrict__ Mtd, float* __restrict__ b1eff) {
    int i = blockIdx.x * 256 + threadIdx.x;
    if (i < 256 * 32) {
        int o = i >> 5, col = i & 31;
        float s = 0.f;
        const float* w1d = msg_w1 + (size_t)o * 576 + 544;
#pragma unroll
        for (int c = 0; c < 32; ++c) s += w1d[c] * tw2[c * 32 + col];
        Mtd[i] = s;
        if (col == 0) {
            float sb = b1[o];
#pragma unroll
            for (int c = 0; c < 32; ++c) sb += w1d[c] * tb2[c];
            b1eff[o] = sb;
        }
    }
}

// fused: blocks [0,1024) = dst-degree counts, [1024,1536) = timestamp max
__global__ void k_counts_tmax(const int* __restrict__ ei, float* __restrict__ counts,
                              const float* __restrict__ ts, int* __restrict__ out) {
    if (blockIdx.x < 1024) {
        int stride = 1024 * 256;
        for (int i = blockIdx.x * 256 + threadIdx.x; i < NE; i += stride)
            atomicAdd(&counts[ei[NE + i]], 1.f);
    } else {
        float m = -INFINITY;
        int stride = 512 * 256;
        for (int i = (blockIdx.x - 1024) * 256 + threadIdx.x; i < NE; i += stride)
            m = fmaxf(m, ts[i]);
        atomicMax(out, enc_f(m));
    }
}

// ---------- CSR build ----------
__global__ void k_scan1(const float* __restrict__ counts, int* __restrict__ rowptr,
                        int* __restrict__ bsum) {
    __shared__ int sh[256];
    int t = threadIdx.x;
    int i = blockIdx.x * 256 + t;
    int v = (i < NN) ? ((int)counts[i] + 1) : 0;
    sh[t] = v;
    __syncthreads();
    for (int off = 1; off < 256; off <<= 1) {
        int x = (t >= off) ? sh[t - off] : 0;
        __syncthreads();
        sh[t] += x;
        __syncthreads();
    }
    if (i < NN) rowptr[i + 1] = sh[t];
    if (t == 255) bsum[blockIdx.x] = sh[255];
}

__global__ void k_scan2(int* __restrict__ bsum, int nb) {
    __shared__ int sh[512];
    int t = threadIdx.x;
    sh[t] = (t < nb) ? bsum[t] : 0;
    __syncthreads();
    for (int off = 1; off < 512; off <<= 1) {
        int x = (t >= off) ? sh[t - off] : 0;
        __syncthreads();
        sh[t] += x;
        __syncthreads();
    }
    if (t < nb) bsum[t] = sh[t];
}

// finalize rowptr and seed both fill cursors (node CSR + edge-only list)
__global__ void k_scan3(int* __restrict__ rowptr, const int* __restrict__ bsum,
                        int* __restrict__ fillp, int* __restrict__ fillE) {
    int i = blockIdx.x * 256 + threadIdx.x;
    if (i == 0) {
        rowptr[0] = 0;
        fillp[0] = 0;
        fillE[0] = 0;
    }
    if (i < NN) {
        int b = i >> 8;
        int off = b > 0 ? bsum[b - 1] : 0;
        int v = rowptr[i + 1] + off;
        rowptr[i + 1] = v;
        if (i + 1 < NN) {
            fillp[i + 1] = v;
            fillE[i + 1] = v - (i + 1);
        }
    }
}

// fused node-CSR fill + edge-list fill (segment dispatch)
__global__ void k_fill_both(const int* __restrict__ ei, int* __restrict__ fillp,
                            int* __restrict__ colidx, int* __restrict__ fillE,
                            int* __restrict__ esrc, int* __restrict__ edst) {
    int i = blockIdx.x * 256 + threadIdx.x;
    if (i < NE) {
        int d = ei[NE + i];
        int pos = atomicAdd(&fillp[d], 1);
        colidx[pos] = ei[i];
    } else if (i < NE + NN) {
        int n = i - NE;
        int pos = atomicAdd(&fillp[n], 1);
        colidx[pos] = n;
    } else {
        int j = i - (NE + NN);
        if (j < NE) {
            int d = ei[NE + j];
            int pos = atomicAdd(&fillE[d], 1);
            esrc[pos] = ei[j];
            edst[pos] = d;
        }
    }
}

// ---------- per-node precompute: P13/P2 + bf16 copy of mem (membf) ----------
__global__ __launch_bounds__(512, 4) void k_pre1(
    const float* __restrict__ mem, const float* __restrict__ x,
    const unsigned short* __restrict__ w1ap, const unsigned short* __restrict__ w1bp,
    const unsigned short* __restrict__ w1cp,
    unsigned short* __restrict__ P13, unsigned short* __restrict__ P2,
    unsigned short* __restrict__ membf) {
    __shared__ unsigned short Af[2 * 8 * GPLANE];
    __shared__ unsigned short Axf[2 * 512];
    const int t = threadIdx.x;
    const int lane = t & 63, w = t >> 6;
    const int row0 = blockIdx.x * 32;
    const int frow = lane & 15, hi = lane >> 4;
    const int half = w >> 2, cq = w & 3;

    {
        int sr = t >> 4, sq = t & 15;
        int row = row0 + sr;
        const float* pm = mem + (size_t)row * 256 + sq * 16;
        int smq = sr >> 4, sfr = sr & 15;
#pragma unroll
        for (int j2 = 0; j2 < 2; ++j2) {
            int k8 = sq * 16 + j2 * 8;
            int st = k8 >> 5, kq = (k8 >> 3) & 3;
            float4 m0 = *(const float4*)(pm + j2 * 8);
            float4 m1 = *(const float4*)(pm + j2 * 8 + 4);
            ushort8v um;
            um[0] = f2bf(m0.x); um[1] = f2bf(m0.y); um[2] = f2bf(m0.z); um[3] = f2bf(m0.w);
            um[4] = f2bf(m1.x); um[5] = f2bf(m1.y); um[6] = f2bf(m1.z); um[7] = f2bf(m1.w);
            *(ushort8v*)&Af[((smq * 8) + st) * GPLANE + (kq * 16 + sfr) * 8] = um;
            *(ushort8v*)(membf + (size_t)row * 256 + k8) = um;
        }
    }
    if (t < 128) {
        int sr = t >> 2, sq = t & 3;
        int row = row0 + sr;
        const float* px = x + (size_t)row * 32 + sq * 8;
        float4 v0 = *(const float4*)px, v1 = *(const float4*)(px + 4);
        ushort8v u;
        u[0] = f2bf(v0.x); u[1] = f2bf(v0.y); u[2] = f2bf(v0.z); u[3] = f2bf(v0.w);
        u[4] = f2bf(v1.x); u[5] = f2bf(v1.y); u[6] = f2bf(v1.z); u[7] = f2bf(v1.w);
        *(ushort8v*)&Axf[(sr >> 4) * 512 + (sq * 16 + (sr & 15)) * 8] = u;
    }
    __syncthreads();

    f32x4 acc[2][4];
#pragma unroll
    for (int mf = 0; mf < 2; ++mf)
#pragma unroll
        for (int c = 0; c < 4; ++c) acc[mf][c] = (f32x4){0, 0, 0, 0};

    const unsigned short* wp = half ? w1bp : w1ap;
    for (int step = 0; step < 8; ++step) {
        bf16x8 aA[2];
#pragma unroll
        for (int mf = 0; mf < 2; ++mf)
            aA[mf] = *(const bf16x8*)&Af[((mf * 8) + step) * GPLANE + lane * 8];
#pragma unroll
        for (int ctl = 0; ctl < 4; ++ctl) {
            bf16x8 b = *(const bf16x8*)(wp + (((size_t)step * 4 + cq) * 4 + ctl) * 512 + lane * 8);
#pragma unroll
            for (int mf = 0; mf < 2; ++mf)
                acc[mf][ctl] = __builtin_amdgcn_mfma_f32_16x16x32_bf16(aA[mf], b, acc[mf][ctl], 0, 0, 0);
        }
    }
    if (half == 0) {
        bf16x8 aX[2];
#pragma unroll
        for (int mf = 0; mf < 2; ++mf)
            aX[mf] = *(const bf16x8*)&Axf[mf * 512 + lane * 8];
#pragma unroll
        for (int ctl = 0; ctl < 4; ++ctl) {
            bf16x8 b = *(const bf16x8*)(w1cp + (((size_t)0 * 4 + cq) * 4 + ctl) * 512 + lane * 8);
#pragma unroll
            for (int mf = 0; mf < 2; ++mf)
                acc[mf][ctl] = __builtin_amdgcn_mfma_f32_16x16x32_bf16(aX[mf], b, acc[mf][ctl], 0, 0, 0);
        }
    }
    unsigned short* P = half ? P2 : P13;
#pragma unroll
    for (int mf = 0; mf < 2; ++mf)
#pragma unroll
        for (int ctl = 0; ctl < 4; ++ctl) {
            int col = cq * 64 + ctl * 16 + frow;
#pragma unroll
            for (int r = 0; r < 4; ++r) {
                int row = row0 + mf * 16 + hi * 4 + r;
                P[(size_t)row * 256 + col] = f2bf(acc[mf][ctl][r]);
            }
        }
}

// ---------- edge message kernel, 512 thr (8 waves x 64x32 out) ----------
__global__ __launch_bounds__(512, 4) void k_msg_mfma(
    const int* __restrict__ ct, const float* __restrict__ lut,
    const int* __restrict__ esrc, const int* __restrict__ edst,
    const unsigned short* __restrict__ P13, const unsigned short* __restrict__ P2,
    const unsigned short* __restrict__ wtdp, const float* __restrict__ b1eff,
    const unsigned short* __restrict__ w2p, const float* __restrict__ b2,
    const float* __restrict__ tw1, const float* __restrict__ tb1,
    float* __restrict__ agg) {
    __shared__ unsigned short As[64][40];
    __shared__ unsigned short Hs[64][264];
    __shared__ int Da[64];

    const int t = threadIdx.x;
    const int lane = t & 63, wave = t >> 6;
    const int row0 = blockIdx.x * 64;
    const int frow = lane & 15;
    const int fk = (lane >> 4) * 8;
    const int hi = lane >> 4;
    const int wb = wave >> 1;
    const int wn = (wave & 1) * 2;

    if (t < 64) {
        int e = row0 + t;
        Da[t] = (e < NE) ? edst[e] : -1;
    }

    const int srow = t >> 3;
    const int sj = t & 7;
    const int eIdx = row0 + srow;
    const bool ev = eIdx < NE;
    const int s_e = ev ? esrc[eIdx] : 0;
    const int d_e = ev ? edst[eIdx] : 0;

    {
        float ctv = dec_f(*ct);
        float dt = ev ? (ctv - fmaxf(lut[s_e], lut[d_e])) : 0.f;
        ushort4 u;
        int c0 = sj * 4;
        u.x = f2bf(fmaxf(dt * tw1[c0 + 0] + tb1[c0 + 0], 0.f));
        u.y = f2bf(fmaxf(dt * tw1[c0 + 1] + tb1[c0 + 1], 0.f));
        u.z = f2bf(fmaxf(dt * tw1[c0 + 2] + tb1[c0 + 2], 0.f));
        u.w = f2bf(fmaxf(dt * tw1[c0 + 3] + tb1[c0 + 3], 0.f));
        *(ushort4*)&As[srow][c0] = u;
    }
    // Hpre = bf16(P13[s] + P2[d]): single 16B gathers per chunk
#pragma unroll
    for (int q = 0; q < 4; ++q) {
        int c = sj * 8 + q * 64;
        ushort8v av = *(const ushort8v*)(P13 + (size_t)s_e * 256 + c);
        ushort8v bv = *(const ushort8v*)(P2 + (size_t)d_e * 256 + c);
        ushort8v u;
#pragma unroll
        for (int j = 0; j < 8; ++j) u[j] = f2bf(bf2f(av[j]) + bf2f(bv[j]));
        *(ushort8v*)&Hs[srow][c] = u;
    }
    __syncthreads();

    f32x4 acc[4][2];
#pragma unroll
    for (int m = 0; m < 4; m++)
#pragma unroll
        for (int n = 0; n < 2; n++) acc[m][n] = (f32x4){0.f, 0.f, 0.f, 0.f};

    {
        bf16x8 a[4];
#pragma unroll
        for (int m = 0; m < 4; m++)
            a[m] = *(const bf16x8*)&As[m * 16 + frow][fk];
#pragma unroll
        for (int n = 0; n < 2; n++) {
            bf16x8 b = *(const bf16x8*)(wtdp + (((size_t)0 * 4 + wb) * 4 + (wn + n)) * 512 + lane * 8);
#pragma unroll
            for (int m = 0; m < 4; m++)
                acc[m][n] = __builtin_amdgcn_mfma_f32_16x16x32_bf16(a[m], b, acc[m][n], 0, 0, 0);
        }
    }
#pragma unroll
    for (int n = 0; n < 2; n++) {
        int c = wave * 32 + n * 16 + frow;
        float bb = b1eff[c];
#pragma unroll
        for (int m = 0; m < 4; m++) {
#pragma unroll
            for (int r = 0; r < 4; r++) {
                int rr = m * 16 + hi * 4 + r;
                float v = acc[m][n][r] + bf2f(Hs[rr][c]) + bb;
                Hs[rr][c] = f2bf(fmaxf(v, 0.f));
            }
            acc[m][n] = (f32x4){0.f, 0.f, 0.f, 0.f};
        }
    }
    __syncthreads();

    bf16x8 bnext[2];
#pragma unroll
    for (int n = 0; n < 2; n++)
        bnext[n] = *(const bf16x8*)(w2p + (((size_t)0 * 4 + wb) * 4 + (wn + n)) * 512 + lane * 8);
    for (int step = 0; step < 8; ++step) {
        const int k0 = step * 32;
        bf16x8 bcur[2];
#pragma unroll
        for (int n = 0; n < 2; n++) bcur[n] = bnext[n];
        if (step < 7) {
#pragma unroll
            for (int n = 0; n < 2; n++)
                bnext[n] = *(const bf16x8*)(w2p + (((size_t)(step + 1) * 4 + wb) * 4 + (wn + n)) * 512 + lane * 8);
        }
        bf16x8 a[4];
#pragma unroll
        for (int m = 0; m < 4; m++)
            a[m] = *(const bf16x8*)&Hs[m * 16 + frow][k0 + fk];
#pragma unroll
        for (int m = 0; m < 4; m++)
#pragma unroll
            for (int n = 0; n < 2; n++)
                acc[m][n] = __builtin_amdgcn_mfma_f32_16x16x32_bf16(a[m], bcur[n], acc[m][n], 0, 0, 0);
    }

    __syncthreads();
    {
        float bb2[2];
#pragma unroll
        for (int n = 0; n < 2; n++) bb2[n] = b2[wave * 32 + n * 16 + frow];
#pragma unroll
        for (int m = 0; m < 4; m++) {
            int rbase = m * 16 + hi * 4;
#pragma unroll
            for (int r = 0; r < 4; r++) {
#pragma unroll
                for (int n = 0; n < 2; n++)
                    Hs[rbase + r][wave * 32 + n * 16 + frow] = f2bf(acc[m][n][r] + bb2[n]);
            }
        }
        __syncthreads();

        int nrows = min(64, NE - row0);
        int col = t & 255;
        int rs = (t >> 8) * 32;
        int re = min(nrows, rs + 32);
        if (rs < re) {
            float run = 0.f;
            int cur = Da[rs];
            for (int i = rs; i < re; ++i) {
                int d = Da[i];
                if (d != cur) {
                    atomicAdd(agg + (size_t)cur * 256 + col, run);
                    run = 0.f;
                    cur = d;
                }
                run += bf2f(Hs[i][col]);
            }
            atomicAdd(agg + (size_t)cur * 256 + col, run);
        }
    }
}

// ---------- GRU, bf16 MFMA v9: v8 + division-free fast gates ----------
__global__ __launch_bounds__(1024, 8) void k_gru_mfma(
    const float* __restrict__ agg, const unsigned short* __restrict__ membf,
    const float* __restrict__ counts,
    const unsigned short* __restrict__ pwih, const unsigned short* __restrict__ pwhh,
    const float* __restrict__ bih, const float* __restrict__ bhh,
    unsigned short* __restrict__ memout) {
    __shared__ unsigned short Af[2 * 2 * 8 * GPLANE];
    const int t = threadIdx.x;
    const int lane = t & 63, w = t >> 6;       // wave 0..15
    const int row0 = blockIdx.x * 32;
    const int frow = lane & 15, hi = lane >> 4;
    const int cqp = w >> 2;                     // 64-col block (0..3)
    const int ctl = w & 3;                      // 16-col frag within it

    // stage A once: 1024 threads x 8 floats = 32 rows x 256 cols
    {
        int sr = t >> 5, sq = t & 31;           // row 0..31, 8-float chunk 0..31
        int row = row0 + sr;
        float inv = 1.f / fmaxf(counts[row], 1.f);
        int k8 = sq * 8;
        int st = k8 >> 5, kq = (k8 >> 3) & 3;
        const float* pa = agg + (size_t)row * 256 + k8;
        const unsigned short* pm = membf + (size_t)row * 256 + k8;
        float4 a0 = *(const float4*)pa;
        float4 a1 = *(const float4*)(pa + 4);
        ushort8v um = *(const ushort8v*)pm;
        ushort8v ua;
        ua[0] = f2bf(a0.x * inv); ua[1] = f2bf(a0.y * inv); ua[2] = f2bf(a0.z * inv); ua[3] = f2bf(a0.w * inv);
        ua[4] = f2bf(a1.x * inv); ua[5] = f2bf(a1.y * inv); ua[6] = f2bf(a1.z * inv); ua[7] = f2bf(a1.w * inv);
        int smq = sr >> 4, sfr = sr & 15;
        int pos = kq * 16 + sfr;
        *(ushort8v*)&Af[(((0 * 2 + smq) * 8) + st) * GPLANE + pos * 8] = ua;
        *(ushort8v*)&Af[(((1 * 2 + smq) * 8) + st) * GPLANE + pos * 8] = um;
    }
    __syncthreads();

    f32x4 rpre[2], zpre[2], inn[2], hn[2];
#pragma unroll
    for (int mf = 0; mf < 2; ++mf) {
        rpre[mf] = (f32x4){0, 0, 0, 0};
        zpre[mf] = (f32x4){0, 0, 0, 0};
        inn[mf]  = (f32x4){0, 0, 0, 0};
        hn[mf]   = (f32x4){0, 0, 0, 0};
    }

    for (int step = 0; step < 8; ++step) {
        bf16x8 aA[2], aM[2];
#pragma unroll
        for (int mf = 0; mf < 2; ++mf) {
            aA[mf] = *(const bf16x8*)&Af[(((0 * 2 + mf) * 8) + step) * GPLANE + lane * 8];
            aM[mf] = *(const bf16x8*)&Af[(((1 * 2 + mf) * 8) + step) * GPLANE + lane * 8];
        }
        size_t o_r = (((size_t)step * 12 + 0 * 4 + cqp) * 4 + ctl) * 512 + lane * 8;
        size_t o_z = (((size_t)step * 12 + 1 * 4 + cqp) * 4 + ctl) * 512 + lane * 8;
        size_t o_n = (((size_t)step * 12 + 2 * 4 + cqp) * 4 + ctl) * 512 + lane * 8;
        bf16x8 bIr = *(const bf16x8*)(pwih + o_r);
        bf16x8 bHr = *(const bf16x8*)(pwhh + o_r);
        bf16x8 bIz = *(const bf16x8*)(pwih + o_z);
        bf16x8 bHz = *(const bf16x8*)(pwhh + o_z);
        bf16x8 bIn = *(const bf16x8*)(pwih + o_n);
        bf16x8 bHn = *(const bf16x8*)(pwhh + o_n);
#pragma unroll
        for (int mf = 0; mf < 2; ++mf) {
            rpre[mf] = __builtin_amdgcn_mfma_f32_16x16x32_bf16(aA[mf], bIr, rpre[mf], 0, 0, 0);
            rpre[mf] = __builtin_amdgcn_mfma_f32_16x16x32_bf16(aM[mf], bHr, rpre[mf], 0, 0, 0);
            zpre[mf] = __builtin_amdgcn_mfma_f32_16x16x32_bf16(aA[mf], bIz, zpre[mf], 0, 0, 0);
            zpre[mf] = __builtin_amdgcn_mfma_f32_16x16x32_bf16(aM[mf], bHz, zpre[mf], 0, 0, 0);
            inn[mf]  = __builtin_amdgcn_mfma_f32_16x16x32_bf16(aA[mf], bIn, inn[mf], 0, 0, 0);
            hn[mf]   = __builtin_amdgcn_mfma_f32_16x16x32_bf16(aM[mf], bHn, hn[mf], 0, 0, 0);
        }
    }

    const int col = cqp * 64 + ctl * 16 + frow;
    const float br = bih[col] + bhh[col];
    const float bz = bih[256 + col] + bhh[256 + col];
    const float bin = bih[512 + col];
    const float bhn = bhh[512 + col];
#pragma unroll
    for (int mf = 0; mf < 2; ++mf)
#pragma unroll
        for (int r = 0; r < 4; ++r) {
            int row = row0 + mf * 16 + hi * 4 + r;
            float cnt = counts[row];
            // division-free fast gates: sigmoid = rcp(1+exp(-x)),
            // tanh(y) = (1-t)*rcp(1+t), t = exp(-2*max(y,-44)) <= e^88 (finite)
            float er = __expf(-(rpre[mf][r] + br));
            float rg = __builtin_amdgcn_rcpf(1.f + er);
            float ez = __expf(-(zpre[mf][r] + bz));
            float zg = __builtin_amdgcn_rcpf(1.f + ez);
            float y = inn[mf][r] + bin + rg * (hn[mf][r] + bhn);
            float ty = __expf(-2.f * fmaxf(y, -44.f));
            float ng = (1.f - ty) * __builtin_amdgcn_rcpf(1.f + ty);
            int pos = ((col >> 3) & 3) * 16 + (hi * 4 + r);
            float hp = bf2f(Af[(((1 * 2 + mf) * 8) + (col >> 5)) * GPLANE + pos * 8 + (col & 7)]);
            memout[(size_t)row * 256 + col] = f2bf((cnt > 0.f) ? ((1.f - zg) * ng + zg * hp) : hp);
        }
}

// ---------- GAT xh GEMM + attention-logit fusion; LDS-staged A tile ----------
__global__ __launch_bounds__(256, 4) void k_xh_mfma(
    const unsigned short* __restrict__ A, const unsigned short* __restrict__ wp,
    const float* __restrict__ asrc, const float* __restrict__ adst,
    unsigned short* __restrict__ xh, float* __restrict__ als, float* __restrict__ ald) {
    __shared__ unsigned short Af[4 * 8 * GPLANE];
    const int t = threadIdx.x;
    const int lane = t & 63, w = t >> 6;
    const int row0 = blockIdx.x * 64;
    const int frow = lane & 15, hi = lane >> 4;

    // stage 64 rows x 256 cols (bf16, pure relayout) into fragment-major LDS.
    {
        int sr = t >> 2, sq = t & 3;
        int row = min(row0 + sr, NN - 1);
        const unsigned short* pa = A + (size_t)row * 256 + sq * 64;
        int rg = sr >> 4, fr = sr & 15;
#pragma unroll
        for (int j = 0; j < 8; ++j) {
            int k8 = sq * 64 + j * 8;
            int st = k8 >> 5, kq = (k8 >> 3) & 3;
            *(ushort8v*)&Af[((rg * 8) + st) * GPLANE + (kq * 16 + fr) * 8] =
                *(const ushort8v*)(pa + j * 8);
        }
    }
    __syncthreads();

    f32x4 acc[4][4];
#pragma unroll
    for (int m = 0; m < 4; m++)
#pragma unroll
        for (int c = 0; c < 4; c++) acc[m][c] = (f32x4){0, 0, 0, 0};

    for (int step = 0; step < 8; ++step) {
        bf16x8 a[4];
#pragma unroll
        for (int m = 0; m < 4; ++m)
            a[m] = *(const bf16x8*)&Af[((m * 8) + step) * GPLANE + lane * 8];
#pragma unroll
        for (int ctl = 0; ctl < 4; ++ctl) {
            bf16x8 b = *(const bf16x8*)(wp + (((size_t)step * 4 + w) * 4 + ctl) * 512 + lane * 8);
#pragma unroll
            for (int m = 0; m < 4; ++m)
                acc[m][ctl] = __builtin_amdgcn_mfma_f32_16x16x32_bf16(a[m], b, acc[m][ctl], 0, 0, 0);
        }
    }

    float asv[4], adv[4];
#pragma unroll
    for (int ctl = 0; ctl < 4; ++ctl) {
        asv[ctl] = asrc[w * 64 + ctl * 16 + frow];
        adv[ctl] = adst[w * 64 + ctl * 16 + frow];
    }
#pragma unroll
    for (int m = 0; m < 4; ++m) {
        float ps[4] = {0, 0, 0, 0}, pd[4] = {0, 0, 0, 0};
#pragma unroll
        for (int ctl = 0; ctl < 4; ++ctl) {
            int col = w * 64 + ctl * 16 + frow;
#pragma unroll
            for (int r = 0; r < 4; ++r) {
                float v = acc[m][ctl][r];
                ps[r] += v * asv[ctl];
                pd[r] += v * adv[ctl];
                int row = row0 + m * 16 + hi * 4 + r;
                if (row < NN) xh[(size_t)row * 256 + col] = f2bf(v);
            }
        }
#pragma unroll
        for (int off = 1; off < 16; off <<= 1) {
#pragma unroll
            for (int r = 0; r < 4; ++r) {
                ps[r] += __shfl_xor(ps[r], off, 64);
                pd[r] += __shfl_xor(pd[r], off, 64);
            }
        }
        if (frow == 0) {
#pragma unroll
            for (int r = 0; r < 4; ++r) {
                int row = row0 + m * 16 + hi * 4 + r;
                if (row < NN) { als[row * 4 + w] = ps[r]; ald[row * 4 + w] = pd[r]; }
            }
        }
    }
}

// ---------- fused GAT edge-softmax + aggregate, CSR, single-pass ----------
__global__ __launch_bounds__(256) void k_gat_csr(
    const int* __restrict__ rowptr, const int* __restrict__ colidx,
    const float* __restrict__ als, const float* __restrict__ ald,
    const unsigned short* __restrict__ xh, const float* __restrict__ bias,
    unsigned short* __restrict__ outb) {
    int d = blockIdx.x * 4 + (threadIdx.x >> 6);
    if (d >= NN) return;
    int lane = threadIdx.x & 63;
    int h = lane >> 4;
    int beg = rowptr[d], end = rowptr[d + 1];
    float aldv = ald[d * 4 + h];

    float den = 0.f;
    float a0 = 0.f, a1 = 0.f, a2 = 0.f, a3 = 0.f;
    for (int p = beg; p < end; ++p) {
        int s = colidx[p];
        float e = als[s * 4 + h] + aldv;
        e = e > 0.f ? e : 0.2f * e;
        float pw = __expf(e);
        den += pw;
        ushort4 uv = *(const ushort4*)(xh + (size_t)s * 256 + lane * 4);
        a0 += pw * bf2f(uv.x);
        a1 += pw * bf2f(uv.y);
        a2 += pw * bf2f(uv.z);
        a3 += pw * bf2f(uv.w);
    }
    float inv = 1.f / den;
    int c = lane * 4;
    float4 bv = *(const float4*)(bias + c);
    float ox = a0 * inv + bv.x; ox = ox > 0.f ? ox : expm1f(ox);
    float oy = a1 * inv + bv.y; oy = oy > 0.f ? oy : expm1f(oy);
    float oz = a2 * inv + bv.z; oz = oz > 0.f ? oz : expm1f(oz);
    float ow = a3 * inv + bv.w; ow = ow > 0.f ? ow : expm1f(ow);
    ushort4 o;
    o.x = f2bf(ox); o.y = f2bf(oy); o.z = f2bf(oz); o.w = f2bf(ow);
    *(ushort4*)(outb + (size_t)d * 256 + c) = o;
}

__global__ __launch_bounds__(256) void k_pool(const unsigned short* __restrict__ h,
                                              const int* __restrict__ batch, float* __restrict__ gsum) {
    int t = threadIdx.x;
    const int per = (NN + gridDim.x - 1) / gridDim.x;
    int n0 = blockIdx.x * per, n1 = min(NN, n0 + per);
    float s = 0.f, cnt = 0.f;
    for (int n = n0; n < n1; n++) {
        if (batch[n] == 0) {
            s += bf2f(h[(size_t)n * 256 + t]);
            cnt += 1.f;
        }
    }
    atomicAdd(&gsum[t], s);
    if (t == 0) atomicAdd(&gsum[256], cnt);
}

__global__ void k_cls(const float* __restrict__ gsum, const float* __restrict__ w1,
                      const float* __restrict__ b1, const float* __restrict__ w2,
                      const float* __restrict__ b2, float* __restrict__ out) {
    __shared__ float g[256];
    __shared__ float hid[128];
    int t = threadIdx.x;
    float gc = gsum[256];
    g[t] = gsum[t] / gc;
    __syncthreads();
    if (t < 128) {
        float s = b1[t];
        for (int k = 0; k < 256; k++) s += g[k] * w1[t * 256 + k];
        hid[t] = fmaxf(s, 0.f);
    }
    __syncthreads();
    if (t < 2) {
        float s = b2[t];
        for (int k = 0; k < 128; k++) s += hid[k] * w2[t * 128 + k];
        out[t] = s;
    }
}

// ---------- launch ----------
extern "C" void kernel_launch(void* const* d_in, const int* in_sizes, int n_in,
                              void* d_out, int out_size, void* d_ws, size_t ws_size,
                              hipStream_t stream) {
    const float* xv      = (const float*)d_in[0];
    const float* tsv     = (const float*)d_in[1];
    const float* nodemem = (const float*)d_in[2];
    const float* lut     = (const float*)d_in[3];
    const float* msg_w1  = (const float*)d_in[4];
    const float* msg_b1  = (const float*)d_in[5];
    const float* msg_w2  = (const float*)d_in[6];
    const float* msg_b2  = (const float*)d_in[7];
    const float* time_w1 = (const float*)d_in[8];
    const float* time_b1 = (const float*)d_in[9];
    const float* time_w2 = (const float*)d_in[10];
    const float* time_b2 = (const float*)d_in[11];
    const float* gru_wih = (const float*)d_in[12];
    const float* gru_whh = (const float*)d_in[13];
    const float* gru_bih = (const float*)d_in[14];
    const float* gru_bhh = (const float*)d_in[15];
    const float* gat1_w    = (const float*)d_in[16];
    const float* gat1_asrc = (const float*)d_in[17];
    const float* gat1_adst = (const float*)d_in[18];
    const float* gat1_b    = (const float*)d_in[19];
    const float* gat2_w    = (const float*)d_in[20];
    const float* gat2_asrc = (const float*)d_in[21];
    const float* gat2_adst = (const float*)d_in[22];
    const float* gat2_b    = (const float*)d_in[23];
    const float* cls_w1 = (const float*)d_in[24];
    const float* cls_b1 = (const float*)d_in[25];
    const float* cls_w2 = (const float*)d_in[26];
    const float* cls_b2 = (const float*)d_in[27];
    const int* ei    = (const int*)d_in[28];
    const int* batch = (const int*)d_in[29];
    float* out = (float*)d_out;

    char* wsb = (char*)d_ws;
    size_t off = 0;
    auto carve = [&](size_t bytes) {
        char* p = wsb + off;
        off += (bytes + 255) & ~(size_t)255;
        return p;
    };
    int*   curtime = (int*)carve(4);
    unsigned short* w1ap = (unsigned short*)carve((size_t)256 * 256 * 2);
    unsigned short* w1bp = (unsigned short*)carve((size_t)256 * 256 * 2);
    unsigned short* w1cp = (unsigned short*)carve((size_t)256 * 32 * 2);
    unsigned short* wtdp = (unsigned short*)carve((size_t)256 * 32 * 2);
    unsigned short* w2p  = (unsigned short*)carve((size_t)256 * 256 * 2);
    unsigned short* wihp = (unsigned short*)carve((size_t)768 * 256 * 2);
    unsigned short* whhp = (unsigned short*)carve((size_t)768 * 256 * 2);
    unsigned short* g1p  = (unsigned short*)carve((size_t)256 * 256 * 2);
    unsigned short* g2p  = (unsigned short*)carve((size_t)256 * 256 * 2);
    float* Mtd   = (float*)carve((size_t)256 * 32 * 4);
    float* b1eff = (float*)carve(256 * 4);
    unsigned short* P13  = (unsigned short*)carve((size_t)NN * 256 * 2);
    unsigned short* P2   = (unsigned short*)carve((size_t)NN * 256 * 2);
    unsigned short* membf = (unsigned short*)carve((size_t)NN * 256 * 2);
    float* als    = (float*)carve((size_t)NN * 4 * 4);
    float* ald    = (float*)carve((size_t)NN * 4 * 4);
    float* counts = (float*)carve((size_t)NN * 4);
    float* gsum   = (float*)carve(257 * 4);
    int*   rowptr = (int*)carve((size_t)(NN + 1) * 4);
    int*   colidx = (int*)carve((size_t)(NE + NN) * 4);
    int*   fillp  = (int*)carve((size_t)NN * 4);
    int*   bsum   = (int*)carve(512 * 4);
    int*   esrc   = (int*)carve((size_t)NE * 4);
    int*   edst   = (int*)carve((size_t)NE * 4);
    int*   fillE  = (int*)carve((size_t)NN * 4);
    float* R1     = (float*)carve((size_t)NN * 256 * 4);  // agg -> xh1(bf16) -> xh2(bf16)
    float* R2     = (float*)carve((size_t)NN * 256 * 4);  // memo/outb1/outb2 (bf16)

    if (ws_size < off) {
        k_dbg<<<1, 1, 0, stream>>>(out, (float)(ws_size >> 20));
        return;
    }

    float* agg   = R1;
    unsigned short* memo  = (unsigned short*)R2;
    unsigned short* xh1   = (unsigned short*)R1;
    unsigned short* xh2   = (unsigned short*)R1;
    unsigned short* outb1 = (unsigned short*)R2;
    unsigned short* outb2 = (unsigned short*)R2;

    // ---- init ----
    hipMemsetAsync(agg, 0, (size_t)NN * 256 * 4, stream);
    hipMemsetAsync(counts, 0, (size_t)NN * 4, stream);
    hipMemsetAsync(gsum, 0, 257 * 4, stream);
    k_fill_i32<<<1, 256, 0, stream>>>(curtime, (int)0x80000000, 1);

    // ---- weight prep: fold te weights, then ALL packs in one launch ----
    k_fold_te<<<32, 256, 0, stream>>>(msg_w1, time_w2, time_b2, msg_b1, Mtd, b1eff);
    k_pack_all<<<2880, 256, 0, stream>>>(msg_w1, Mtd, msg_w2, gru_wih, gru_whh,
                                         gat1_w, gat2_w,
                                         w1ap, w1bp, w1cp, wtdp, w2p,
                                         wihp, whhp, g1p, g2p);

    // ---- counts + timestamp max (fused) + CSR build ----
    k_counts_tmax<<<1536, 256, 0, stream>>>(ei, counts, tsv, curtime);
    k_scan1<<<391, 256, 0, stream>>>(counts, rowptr, bsum);
    k_scan2<<<1, 512, 0, stream>>>(bsum, 391);
    k_scan3<<<391, 256, 0, stream>>>(rowptr, bsum, fillp, fillE);
    k_fill_both<<<2735, 256, 0, stream>>>(ei, fillp, colidx, fillE, esrc, edst);

    // ---- per-node precompute + messages + memory update ----
    k_pre1<<<3125, 512, 0, stream>>>(nodemem, xv, w1ap, w1bp, w1cp, P13, P2, membf);
    k_msg_mfma<<<4688, 512, 0, stream>>>(curtime, lut, esrc, edst, P13, P2,
                                         wtdp, b1eff, w2p, msg_b2,
                                         time_w1, time_b1, agg);
    k_gru_mfma<<<3125, 1024, 0, stream>>>(agg, membf, counts, wihp, whhp,
                                          gru_bih, gru_bhh, memo);

    // ---- GAT layer 1 ----
    k_xh_mfma<<<1563, 256, 0, stream>>>(memo, g1p, gat1_asrc, gat1_adst, xh1, als, ald);
    k_gat_csr<<<25000, 256, 0, stream>>>(rowptr, colidx, als, ald, xh1, gat1_b, outb1);

    // ---- GAT layer 2 ----
    k_xh_mfma<<<1563, 256, 0, stream>>>(outb1, g2p, gat2_asrc, gat2_adst, xh2, als, ald);
    k_gat_csr<<<25000, 256, 0, stream>>>(rowptr, colidx, als, ald, xh2, gat2_b, outb2);

    // ---- pool + classifier ----
    k_pool<<<2048, 256, 0, stream>>>(outb2, batch, gsum);
    k_cls<<<1, 256, 0, stream>>>(gsum, cls_w1, cls_b1, cls_w2, cls_b2, out);
}